// Round 1
// baseline (262.046 us; speedup 1.0000x reference)
//
#include <hip/hip_runtime.h>
#include <hip/hip_bf16.h>

#define S_LEN 2048
#define DIMSZ 1024
#define NH    16
#define HD    64

typedef __attribute__((ext_vector_type(8))) short short8v;
typedef __attribute__((ext_vector_type(4))) short short4v;
typedef __attribute__((ext_vector_type(4))) float f32x4;

__device__ __forceinline__ ushort f2bf(float f) {
  union { float f; unsigned u; } v; v.f = f;
  unsigned u = v.u;
  return (ushort)((u + 0x7FFFu + ((u >> 16) & 1u)) >> 16);
}

// ---------------- RoPE cos/sin table: [s][i] i<32, float2{cos,sin} --------
__global__ __launch_bounds__(256) void rope_table_k(float2* __restrict__ tab) {
  int i = blockIdx.x * 256 + threadIdx.x;      // < 2048*32
  int s = i >> 5, f = i & 31;
  float inv = powf(10000.f, -(float)f * (1.f / 32.f));
  float ang = (float)s * inv;
  tab[i] = make_float2(cosf(ang), sinf(ang));
}

// ---------------- QKV projection + RoPE, bf16 MFMA GEMM -------------------
// C = x @ W^T ; which = blockIdx.z : 0->q(rope), 1->k(rope), 2->v(transposed)
__global__ __launch_bounds__(256) void gemm_qkv_k(
    const float* __restrict__ x,
    const float* __restrict__ Wq, const float* __restrict__ Wk, const float* __restrict__ Wv,
    ushort* __restrict__ qb, ushort* __restrict__ kb, ushort* __restrict__ vtb,
    const float2* __restrict__ rtab)
{
  __shared__ ushort lA[128 * 64];
  __shared__ ushort lB[128 * 64];
  const int t = threadIdx.x;
  const int which = blockIdx.z;
  const float* W = (which == 0) ? Wq : ((which == 1) ? Wk : Wv);
  const int bm = blockIdx.y * 128, bn = blockIdx.x * 128;
  const int w = t >> 6, l = t & 63, lr = l & 15, lg = l >> 4;
  const int wm = (w >> 1) * 64, wn = (w & 1) * 64;
  const int sr = t >> 4, sc = t & 15;

  f32x4 acc[4][4] = {};

  for (int kt = 0; kt < DIMSZ / 64; ++kt) {
    const int k0 = kt * 64;
    __syncthreads();
    for (int i = 0; i < 8; ++i) {
      int r = sr + i * 16;
      float4 va = *((const float4*)(x + (size_t)(bm + r) * DIMSZ + k0) + sc);
      short4v ha;
      ha[0] = (short)f2bf(va.x); ha[1] = (short)f2bf(va.y);
      ha[2] = (short)f2bf(va.z); ha[3] = (short)f2bf(va.w);
      *(short4v*)((char*)lA + r * 128 + ((sc * 8) ^ ((r & 7) << 4))) = ha;
      float4 vb = *((const float4*)(W + (size_t)(bn + r) * DIMSZ + k0) + sc);
      short4v hb;
      hb[0] = (short)f2bf(vb.x); hb[1] = (short)f2bf(vb.y);
      hb[2] = (short)f2bf(vb.z); hb[3] = (short)f2bf(vb.w);
      *(short4v*)((char*)lB + r * 128 + ((sc * 8) ^ ((r & 7) << 4))) = hb;
    }
    __syncthreads();
    for (int kk = 0; kk < 2; ++kk) {
      short8v a[4], b[4];
      for (int mt = 0; mt < 4; ++mt) {
        int row = wm + mt * 16 + lr;
        a[mt] = *(const short8v*)((const char*)lA + row * 128 + ((kk * 64 + lg * 16) ^ ((row & 7) << 4)));
      }
      for (int nt = 0; nt < 4; ++nt) {
        int row = wn + nt * 16 + lr;
        b[nt] = *(const short8v*)((const char*)lB + row * 128 + ((kk * 64 + lg * 16) ^ ((row & 7) << 4)));
      }
      for (int mt = 0; mt < 4; ++mt)
        for (int nt = 0; nt < 4; ++nt)
          acc[mt][nt] = __builtin_amdgcn_mfma_f32_16x16x32_bf16(a[mt], b[nt], acc[mt][nt], 0, 0, 0);
    }
  }

  // epilogue: RoPE (q,k) or transpose-scatter (v)
  for (int mt = 0; mt < 4; ++mt)
    for (int nt = 0; nt < 4; ++nt)
      for (int r = 0; r < 4; ++r) {
        float v = acc[mt][nt][r];
        float partner = __shfl_xor(v, 1);   // all lanes execute: pair column
        int m = bm + wm + mt * 16 + lg * 4 + r;   // global row = b*S + s
        int n = bn + wn + nt * 16 + lr;           // global col = h*64 + d
        int d = n & 63, h = n >> 6;
        int s = m & (S_LEN - 1), bb = m >> 11;
        if (which == 2) {
          vtb[((size_t)(bb * NH + h) * HD + d) * S_LEN + s] = f2bf(v);
        } else {
          float2 cs = rtab[s * 32 + (d >> 1)];
          float o = (d & 1) ? (partner * cs.y + v * cs.x)   // t1*sin + t2*cos
                            : (v * cs.x - partner * cs.y);  // t1*cos - t2*sin
          ushort* dst = (which == 0) ? qb : kb;
          dst[((size_t)(bb * NH + h) * S_LEN + s) * HD + d] = f2bf(o);
        }
      }
}

// ---------------- Flash attention (causal) --------------------------------
// q,k: [b][h][s][64] bf16 ; vt: [b][h][64][s] bf16 ; out ab: [b][s][h*64+d]
__global__ __launch_bounds__(256) void flash_k(
    const ushort* __restrict__ qb, const ushort* __restrict__ kb,
    const ushort* __restrict__ vtb, ushort* __restrict__ ab)
{
  __shared__ ushort lK[64 * 64];
  __shared__ ushort lV[64 * 64];
  __shared__ ushort lP[4][16 * 64];
  const int qt = blockIdx.x, bh = blockIdx.y;
  const int t = threadIdx.x, w = t >> 6, l = t & 63, lr = l & 15, lg = l >> 4;
  const int qw = qt * 64 + w * 16;            // wave's q-row base

  short8v qf[2];
  for (int kk = 0; kk < 2; ++kk)
    qf[kk] = *(const short8v*)(qb + ((size_t)bh * S_LEN + qw + lr) * HD + kk * 32 + lg * 8);

  float m_r[4], l_r[4];
  f32x4 o[4] = {};
  for (int r = 0; r < 4; ++r) { m_r[r] = -1e30f; l_r[r] = 0.f; }

  const int srow = t >> 2, sc2 = (t & 3) * 2;

  for (int kt = 0; kt <= qt; ++kt) {
    const int k0 = kt * 64;
    __syncthreads();
    {
      const ushort* sk = kb + ((size_t)bh * S_LEN + k0 + srow) * HD;
      const ushort* sv = vtb + ((size_t)bh * HD + srow) * S_LEN + k0;
      for (int j = 0; j < 2; ++j) {
        int c = sc2 + j;
        short8v vk = *(const short8v*)(sk + c * 8);
        *(short8v*)((char*)lK + srow * 128 + ((c * 16) ^ ((srow & 7) << 4))) = vk;
        short8v vv = *(const short8v*)(sv + c * 8);
        *(short8v*)((char*)lV + srow * 128 + ((c * 16) ^ ((srow & 7) << 4))) = vv;
      }
    }
    __syncthreads();

    f32x4 sacc[4] = {};
    for (int kk = 0; kk < 2; ++kk)
      for (int jt = 0; jt < 4; ++jt) {
        int row = jt * 16 + lr;
        short8v bf = *(const short8v*)((const char*)lK + row * 128 + ((kk * 64 + lg * 16) ^ ((row & 7) << 4)));
        sacc[jt] = __builtin_amdgcn_mfma_f32_16x16x32_bf16(qf[kk], bf, sacc[jt], 0, 0, 0);
      }

    const bool diag = (kt == qt);
    float p[4][4], rmax[4];
    for (int r = 0; r < 4; ++r) rmax[r] = -1e30f;
    for (int jt = 0; jt < 4; ++jt)
      for (int r = 0; r < 4; ++r) {
        float sv = sacc[jt][r] * 0.125f;
        if (diag && (k0 + jt * 16 + lr > qw + lg * 4 + r)) sv = -1e30f;
        p[jt][r] = sv;
        rmax[r] = fmaxf(rmax[r], sv);
      }
    for (int r = 0; r < 4; ++r) {
      rmax[r] = fmaxf(rmax[r], __shfl_xor(rmax[r], 1));
      rmax[r] = fmaxf(rmax[r], __shfl_xor(rmax[r], 2));
      rmax[r] = fmaxf(rmax[r], __shfl_xor(rmax[r], 4));
      rmax[r] = fmaxf(rmax[r], __shfl_xor(rmax[r], 8));
    }
    float so[4];
    for (int r = 0; r < 4; ++r) {
      float mn = fmaxf(m_r[r], rmax[r]);
      so[r] = __expf(m_r[r] - mn);
      m_r[r] = mn;
      float s = 0.f;
      for (int jt = 0; jt < 4; ++jt) { p[jt][r] = __expf(p[jt][r] - mn); s += p[jt][r]; }
      s += __shfl_xor(s, 1); s += __shfl_xor(s, 2);
      s += __shfl_xor(s, 4); s += __shfl_xor(s, 8);
      l_r[r] = l_r[r] * so[r] + s;
    }
    // stage P (per-wave private LDS), swizzled to match A-frag reads
    for (int jt = 0; jt < 4; ++jt)
      for (int r = 0; r < 4; ++r) {
        int q = lg * 4 + r;
        *(ushort*)((char*)lP[w] + q * 128 + ((jt * 32 + lr * 2) ^ ((q & 7) << 4))) = f2bf(p[jt][r]);
      }
    for (int dt = 0; dt < 4; ++dt)
      for (int r = 0; r < 4; ++r) o[dt][r] *= so[r];
    for (int kk = 0; kk < 2; ++kk) {
      short8v pa = *(const short8v*)((const char*)lP[w] + lr * 128 + ((kk * 64 + lg * 16) ^ ((lr & 7) << 4)));
      for (int dt = 0; dt < 4; ++dt) {
        int row = dt * 16 + lr;
        short8v vb = *(const short8v*)((const char*)lV + row * 128 + ((kk * 64 + lg * 16) ^ ((row & 7) << 4)));
        o[dt] = __builtin_amdgcn_mfma_f32_16x16x32_bf16(pa, vb, o[dt], 0, 0, 0);
      }
    }
  }

  const int bb = bh >> 4, h = bh & 15;
  for (int r = 0; r < 4; ++r) {
    float inv = 1.f / l_r[r];
    int qg = qw + lg * 4 + r;
    for (int dt = 0; dt < 4; ++dt) {
      int d = dt * 16 + lr;
      ab[((size_t)bb * S_LEN + qg) * DIMSZ + h * HD + d] = f2bf(o[dt][r] * inv);
    }
  }
}

// ---------------- Output projection: out = ab @ Wo^T (fp32 out) -----------
__global__ __launch_bounds__(256) void gemm_out_k(
    const ushort* __restrict__ ab, const float* __restrict__ Wo, float* __restrict__ out)
{
  __shared__ ushort lA[128 * 64];
  __shared__ ushort lB[128 * 64];
  const int t = threadIdx.x;
  const int bm = blockIdx.y * 128, bn = blockIdx.x * 128;
  const int w = t >> 6, l = t & 63, lr = l & 15, lg = l >> 4;
  const int wm = (w >> 1) * 64, wn = (w & 1) * 64;
  const int sr8 = t >> 3, sc8 = t & 7;
  const int sr = t >> 4, sc = t & 15;

  f32x4 acc[4][4] = {};

  for (int kt = 0; kt < DIMSZ / 64; ++kt) {
    const int k0 = kt * 64;
    __syncthreads();
    for (int i = 0; i < 4; ++i) {
      int r = sr8 + i * 32;
      short8v v = *(const short8v*)(ab + (size_t)(bm + r) * DIMSZ + k0 + sc8 * 8);
      *(short8v*)((char*)lA + r * 128 + ((sc8 * 16) ^ ((r & 7) << 4))) = v;
    }
    for (int i = 0; i < 8; ++i) {
      int r = sr + i * 16;
      float4 vb = *((const float4*)(Wo + (size_t)(bn + r) * DIMSZ + k0) + sc);
      short4v hb;
      hb[0] = (short)f2bf(vb.x); hb[1] = (short)f2bf(vb.y);
      hb[2] = (short)f2bf(vb.z); hb[3] = (short)f2bf(vb.w);
      *(short4v*)((char*)lB + r * 128 + ((sc * 8) ^ ((r & 7) << 4))) = hb;
    }
    __syncthreads();
    for (int kk = 0; kk < 2; ++kk) {
      short8v a[4], b[4];
      for (int mt = 0; mt < 4; ++mt) {
        int row = wm + mt * 16 + lr;
        a[mt] = *(const short8v*)((const char*)lA + row * 128 + ((kk * 64 + lg * 16) ^ ((row & 7) << 4)));
      }
      for (int nt = 0; nt < 4; ++nt) {
        int row = wn + nt * 16 + lr;
        b[nt] = *(const short8v*)((const char*)lB + row * 128 + ((kk * 64 + lg * 16) ^ ((row & 7) << 4)));
      }
      for (int mt = 0; mt < 4; ++mt)
        for (int nt = 0; nt < 4; ++nt)
          acc[mt][nt] = __builtin_amdgcn_mfma_f32_16x16x32_bf16(a[mt], b[nt], acc[mt][nt], 0, 0, 0);
    }
  }

  for (int mt = 0; mt < 4; ++mt)
    for (int nt = 0; nt < 4; ++nt)
      for (int r = 0; r < 4; ++r) {
        int m = bm + wm + mt * 16 + lg * 4 + r;
        int n = bn + wn + nt * 16 + lr;
        out[(size_t)m * DIMSZ + n] = acc[mt][nt][r];
      }
}

extern "C" void kernel_launch(void* const* d_in, const int* in_sizes, int n_in,
                              void* d_out, int out_size, void* d_ws, size_t ws_size,
                              hipStream_t stream) {
  (void)in_sizes; (void)n_in; (void)out_size; (void)ws_size;
  const float* x  = (const float*)d_in[0];
  const float* Wq = (const float*)d_in[1];
  const float* Wk = (const float*)d_in[2];
  const float* Wv = (const float*)d_in[3];
  const float* Wo = (const float*)d_in[4];
  float* out = (float*)d_out;

  char* ws = (char*)d_ws;
  ushort* qb  = (ushort*)(ws);
  ushort* kb  = (ushort*)(ws + ((size_t)8  << 20));
  ushort* vtb = (ushort*)(ws + ((size_t)16 << 20));
  ushort* ab  = (ushort*)(ws + ((size_t)24 << 20));
  float2* rtab = (float2*)(ws + ((size_t)32 << 20));

  hipLaunchKernelGGL(rope_table_k, dim3(S_LEN * 32 / 256), dim3(256), 0, stream, rtab);
  hipLaunchKernelGGL(gemm_qkv_k, dim3(8, 32, 3), dim3(256), 0, stream,
                     x, Wq, Wk, Wv, qb, kb, vtb, rtab);
  hipLaunchKernelGGL(flash_k, dim3(32, 32), dim3(256), 0, stream, qb, kb, vtb, ab);
  hipLaunchKernelGGL(gemm_out_k, dim3(8, 32), dim3(256), 0, stream, ab, Wo, out);
}

// Round 2
// 167.185 us; speedup vs baseline: 1.5674x; 1.5674x over previous
//
#include <hip/hip_runtime.h>
#include <hip/hip_bf16.h>

#define S_LEN 2048
#define DIMSZ 1024
#define NH    16
#define HD    64

typedef __attribute__((ext_vector_type(8))) short short8v;
typedef __attribute__((ext_vector_type(4))) short short4v;
typedef __attribute__((ext_vector_type(4))) float f32x4;

typedef const __attribute__((address_space(1))) unsigned GU;
typedef __attribute__((address_space(3))) unsigned LU;

__device__ __forceinline__ void gl16(const ushort* g, ushort* l) {
  __builtin_amdgcn_global_load_lds((GU*)g, (LU*)l, 16, 0, 0);
}

__device__ __forceinline__ ushort f2bf(float f) {
  union { float f; unsigned u; } v; v.f = f;
  unsigned u = v.u;
  return (ushort)((u + 0x7FFFu + ((u >> 16) & 1u)) >> 16);
}

// ---------------- fp32 -> bf16 pre-convert (x, Wq|Wk|Wv, Wo) --------------
__global__ __launch_bounds__(256) void cvt_k(
    const float* __restrict__ x, const float* __restrict__ wq,
    const float* __restrict__ wk, const float* __restrict__ wv,
    const float* __restrict__ wo,
    ushort* __restrict__ xb, ushort* __restrict__ wqkvb, ushort* __restrict__ wob)
{
  size_t gid = (size_t)blockIdx.x * 256 + threadIdx.x;
  size_t e0 = gid * 8;
  const float* src; ushort* dst;
  if (e0 < (4u << 20)) { src = x + e0; dst = xb + e0; }
  else if (e0 < (7u << 20)) {
    size_t o = e0 - (4u << 20);
    const float* w = (o < (1u << 20)) ? wq : ((o < (2u << 20)) ? wk : wv);
    src = w + (o & ((1u << 20) - 1)); dst = wqkvb + o;
  } else {
    size_t o = e0 - (7u << 20);
    src = wo + o; dst = wob + o;
  }
  float4 a = *(const float4*)src;
  float4 b = *(const float4*)(src + 4);
  short8v h;
  h[0] = (short)f2bf(a.x); h[1] = (short)f2bf(a.y);
  h[2] = (short)f2bf(a.z); h[3] = (short)f2bf(a.w);
  h[4] = (short)f2bf(b.x); h[5] = (short)f2bf(b.y);
  h[6] = (short)f2bf(b.z); h[7] = (short)f2bf(b.w);
  *(short8v*)dst = h;
}

// ---------------- RoPE cos/sin table: [s][i] i<32, float2{cos,sin} --------
__global__ __launch_bounds__(256) void rope_table_k(float2* __restrict__ tab) {
  int i = blockIdx.x * 256 + threadIdx.x;      // < 2048*32
  int s = i >> 5, f = i & 31;
  float inv = powf(10000.f, -(float)f * (1.f / 32.f));
  float ang = (float)s * inv;
  tab[i] = make_float2(cosf(ang), sinf(ang));
}

// ---------------- QKV projection + RoPE, bf16 MFMA GEMM (gload_lds) -------
__global__ __launch_bounds__(256) void gemm_qkv_k(
    const ushort* __restrict__ xb, const ushort* __restrict__ wqkvb,
    ushort* __restrict__ qb, ushort* __restrict__ kb, ushort* __restrict__ vtb,
    const float2* __restrict__ rtab)
{
  __shared__ ushort lA[128 * 64];
  __shared__ ushort lB[128 * 64];
  const int t = threadIdx.x;
  const int which = blockIdx.z;
  const ushort* W = wqkvb + ((size_t)which << 20);
  const int bm = blockIdx.y * 128, bn = blockIdx.x * 128;
  const int w = t >> 6, l = t & 63, lr = l & 15, lg = l >> 4;
  const int wm = (w >> 1) * 64, wn = (w & 1) * 64;
  const int r8 = l >> 3;
  const int cswz = ((l & 7) ^ r8) * 8;   // pre-swizzled source col (elements)

  f32x4 acc[4][4] = {};

  for (int kt = 0; kt < DIMSZ / 64; ++kt) {
    const int k0 = kt * 64;
    __syncthreads();
    #pragma unroll
    for (int j = 0; j < 4; ++j) {
      int R = w * 32 + j * 8;
      gl16(xb + (size_t)(bm + R + r8) * DIMSZ + k0 + cswz, lA + R * 64);
      gl16(W  + (size_t)(bn + R + r8) * DIMSZ + k0 + cswz, lB + R * 64);
    }
    __syncthreads();
    #pragma unroll
    for (int kk = 0; kk < 2; ++kk) {
      short8v a[4], b[4];
      #pragma unroll
      for (int mt = 0; mt < 4; ++mt) {
        int row = wm + mt * 16 + lr;
        a[mt] = *(const short8v*)((const char*)lA + row * 128 + ((kk * 64 + lg * 16) ^ ((row & 7) << 4)));
      }
      #pragma unroll
      for (int nt = 0; nt < 4; ++nt) {
        int row = wn + nt * 16 + lr;
        b[nt] = *(const short8v*)((const char*)lB + row * 128 + ((kk * 64 + lg * 16) ^ ((row & 7) << 4)));
      }
      #pragma unroll
      for (int mt = 0; mt < 4; ++mt)
        #pragma unroll
        for (int nt = 0; nt < 4; ++nt)
          acc[mt][nt] = __builtin_amdgcn_mfma_f32_16x16x32_bf16(a[mt], b[nt], acc[mt][nt], 0, 0, 0);
    }
  }

  // epilogue: RoPE (q,k) or transpose-scatter (v)
  #pragma unroll
  for (int mt = 0; mt < 4; ++mt)
    #pragma unroll
    for (int nt = 0; nt < 4; ++nt)
      #pragma unroll
      for (int r = 0; r < 4; ++r) {
        float v = acc[mt][nt][r];
        float partner = __shfl_xor(v, 1);
        int m = bm + wm + mt * 16 + lg * 4 + r;   // global row = b*S + s
        int n = bn + wn + nt * 16 + lr;           // global col = h*64 + d
        int d = n & 63, h = n >> 6;
        int s = m & (S_LEN - 1), bb = m >> 11;
        if (which == 2) {
          vtb[((size_t)(bb * NH + h) * HD + d) * S_LEN + s] = f2bf(v);
        } else {
          float2 cs = rtab[s * 32 + (d >> 1)];
          float o = (d & 1) ? (partner * cs.y + v * cs.x)
                            : (v * cs.x - partner * cs.y);
          ushort* dst = (which == 0) ? qb : kb;
          dst[((size_t)(bb * NH + h) * S_LEN + s) * HD + d] = f2bf(o);
        }
      }
}

// ---------------- Flash attention (causal), paired q-tiles ----------------
__device__ __forceinline__ void attn_tile(
    const ushort* lK, const ushort* lV, ushort* lPw,
    const short8v* qf, f32x4* o, float& m2, float& lsum,
    int lr, int lg, bool diag, int wrow)
{
  f32x4 sacc[4] = {};
  #pragma unroll
  for (int kk = 0; kk < 2; ++kk)
    #pragma unroll
    for (int jt = 0; jt < 4; ++jt) {
      int row = jt * 16 + lr;
      short8v kf = *(const short8v*)((const char*)lK + row * 128 + ((kk * 64 + lg * 16) ^ ((row & 7) << 4)));
      sacc[jt] = __builtin_amdgcn_mfma_f32_16x16x32_bf16(kf, qf[kk], sacc[jt], 0, 0, 0);
    }
  const float SC = 0.125f * 1.4426950408889634f;  // scale * log2(e)
  float v2[4][4];
  float rmax = -3e38f;
  #pragma unroll
  for (int jt = 0; jt < 4; ++jt)
    #pragma unroll
    for (int r = 0; r < 4; ++r) {
      float sv = sacc[jt][r] * SC;
      if (diag && (jt * 16 + lg * 4 + r > wrow + lr)) sv = -3e38f;
      v2[jt][r] = sv;
      rmax = fmaxf(rmax, sv);
    }
  rmax = fmaxf(rmax, __shfl_xor(rmax, 16));
  rmax = fmaxf(rmax, __shfl_xor(rmax, 32));
  float mn = fmaxf(m2, rmax);
  float so = exp2f(m2 - mn);
  m2 = mn;
  float pe[4][4];
  float ps = 0.f;
  #pragma unroll
  for (int jt = 0; jt < 4; ++jt)
    #pragma unroll
    for (int r = 0; r < 4; ++r) {
      pe[jt][r] = exp2f(v2[jt][r] - mn);
      ps += pe[jt][r];
    }
  ps += __shfl_xor(ps, 16);
  ps += __shfl_xor(ps, 32);
  lsum = lsum * so + ps;
  #pragma unroll
  for (int jt = 0; jt < 4; ++jt) {
    short4v h;
    #pragma unroll
    for (int r = 0; r < 4; ++r) h[r] = (short)f2bf(pe[jt][r]);
    *(short4v*)((char*)lPw + lr * 128 + ((jt * 32 + lg * 8) ^ ((lr & 7) << 4))) = h;
  }
  #pragma unroll
  for (int r = 0; r < 4; ++r) {
    float sor = __shfl(so, lg * 4 + r);
    #pragma unroll
    for (int dt = 0; dt < 4; ++dt) o[dt][r] *= sor;
  }
  #pragma unroll
  for (int kk = 0; kk < 2; ++kk) {
    short8v pa = *(const short8v*)((const char*)lPw + lr * 128 + ((kk * 64 + lg * 16) ^ ((lr & 7) << 4)));
    #pragma unroll
    for (int dt = 0; dt < 4; ++dt) {
      int row = dt * 16 + lr;
      short8v vb = *(const short8v*)((const char*)lV + row * 128 + ((kk * 64 + lg * 16) ^ ((row & 7) << 4)));
      o[dt] = __builtin_amdgcn_mfma_f32_16x16x32_bf16(pa, vb, o[dt], 0, 0, 0);
    }
  }
}

__device__ __forceinline__ void store_tile(
    ushort* __restrict__ ab, int bh, int qt, int w, int lr, int lg,
    const f32x4* o, float lsum)
{
  int b = bh >> 4, h = bh & 15;
  #pragma unroll
  for (int r = 0; r < 4; ++r) {
    float li = __shfl(lsum, lg * 4 + r);
    float inv = 1.f / li;
    int qg = qt * 64 + w * 16 + lg * 4 + r;
    #pragma unroll
    for (int dt = 0; dt < 4; ++dt)
      ab[((size_t)b * S_LEN + qg) * DIMSZ + h * HD + dt * 16 + lr] = f2bf(o[dt][r] * inv);
  }
}

#define STAGE(c, ktile) do {                                                  \
    int kk0_ = (ktile) * 64;                                                  \
    _Pragma("unroll")                                                         \
    for (int j_ = 0; j_ < 2; ++j_) {                                          \
      int R_ = w * 16 + j_ * 8;                                               \
      gl16(kbh + (size_t)(kk0_ + R_ + r8) * HD + cswz, &lKb[c][R_ * 64]);     \
      gl16(vbh + (size_t)(R_ + r8) * S_LEN + kk0_ + cswz, &lVb[c][R_ * 64]);  \
    }                                                                         \
  } while (0)

__global__ __launch_bounds__(256) void flash_k(
    const ushort* __restrict__ qb, const ushort* __restrict__ kb,
    const ushort* __restrict__ vtb, ushort* __restrict__ ab)
{
  __shared__ ushort lKb[2][64 * 64];
  __shared__ ushort lVb[2][64 * 64];
  __shared__ ushort lP[4][16 * 64];

  // XCD-chunked swizzle: 512 blocks -> 64-block contiguous chunk per XCD
  int id = blockIdx.y * 16 + blockIdx.x;
  int nid = (id & 7) * 64 + (id >> 3);
  const int pr = nid & 15, bh = nid >> 4;
  const int qtA = pr, qtB = 31 - pr;
  const int NT = qtB + 1;

  const int t = threadIdx.x, w = t >> 6, l = t & 63, lr = l & 15, lg = l >> 4;
  const int r8 = l >> 3;
  const int cswz = ((l & 7) ^ r8) * 8;
  const ushort* kbh = kb + (size_t)bh * S_LEN * HD;
  const ushort* vbh = vtb + (size_t)bh * HD * S_LEN;

  short8v qfA[2], qfB[2];
  #pragma unroll
  for (int kk = 0; kk < 2; ++kk) {
    qfA[kk] = *(const short8v*)(qb + ((size_t)bh * S_LEN + qtA * 64 + w * 16 + lr) * HD + kk * 32 + lg * 8);
    qfB[kk] = *(const short8v*)(qb + ((size_t)bh * S_LEN + qtB * 64 + w * 16 + lr) * HD + kk * 32 + lg * 8);
  }

  float mA = -3e38f, lsA = 0.f, mB = -3e38f, lsB = 0.f;
  f32x4 oA[4] = {}, oB[4] = {};

  STAGE(0, 0);
  asm volatile("s_waitcnt vmcnt(0)" ::: "memory");   // drain qf loads + tile0

  for (int kt = 0; kt < NT; ++kt) {
    const int cur = kt & 1;
    if (kt + 1 < NT) {
      STAGE(cur ^ 1, kt + 1);
      asm volatile("s_waitcnt vmcnt(4)" ::: "memory");  // current tile landed
    } else {
      asm volatile("s_waitcnt vmcnt(0)" ::: "memory");
    }
    __builtin_amdgcn_s_barrier();
    asm volatile("" ::: "memory");
    const ushort* lK = lKb[cur];
    const ushort* lV = lVb[cur];
    attn_tile(lK, lV, lP[w], qfB, oB, mB, lsB, lr, lg, kt == qtB, w * 16);
    if (kt <= qtA)
      attn_tile(lK, lV, lP[w], qfA, oA, mA, lsA, lr, lg, kt == qtA, w * 16);
    __builtin_amdgcn_s_barrier();
    asm volatile("" ::: "memory");
  }

  store_tile(ab, bh, qtB, w, lr, lg, oB, lsB);
  store_tile(ab, bh, qtA, w, lr, lg, oA, lsA);
}

// ---------------- Output projection: out = ab @ Wo^T (fp32 out) -----------
__global__ __launch_bounds__(256) void gemm_out_k(
    const ushort* __restrict__ ab, const ushort* __restrict__ wob, float* __restrict__ out)
{
  __shared__ ushort lA[128 * 64];
  __shared__ ushort lB[128 * 64];
  const int t = threadIdx.x;
  const int bm = blockIdx.y * 128, bn = blockIdx.x * 128;
  const int w = t >> 6, l = t & 63, lr = l & 15, lg = l >> 4;
  const int wm = (w >> 1) * 64, wn = (w & 1) * 64;
  const int r8 = l >> 3;
  const int cswz = ((l & 7) ^ r8) * 8;

  f32x4 acc[4][4] = {};

  for (int kt = 0; kt < DIMSZ / 64; ++kt) {
    const int k0 = kt * 64;
    __syncthreads();
    #pragma unroll
    for (int j = 0; j < 4; ++j) {
      int R = w * 32 + j * 8;
      gl16(ab  + (size_t)(bm + R + r8) * DIMSZ + k0 + cswz, lA + R * 64);
      gl16(wob + (size_t)(bn + R + r8) * DIMSZ + k0 + cswz, lB + R * 64);
    }
    __syncthreads();
    #pragma unroll
    for (int kk = 0; kk < 2; ++kk) {
      short8v a[4], b[4];
      #pragma unroll
      for (int mt = 0; mt < 4; ++mt) {
        int row = wm + mt * 16 + lr;
        a[mt] = *(const short8v*)((const char*)lA + row * 128 + ((kk * 64 + lg * 16) ^ ((row & 7) << 4)));
      }
      #pragma unroll
      for (int nt = 0; nt < 4; ++nt) {
        int row = wn + nt * 16 + lr;
        b[nt] = *(const short8v*)((const char*)lB + row * 128 + ((kk * 64 + lg * 16) ^ ((row & 7) << 4)));
      }
      #pragma unroll
      for (int mt = 0; mt < 4; ++mt)
        #pragma unroll
        for (int nt = 0; nt < 4; ++nt)
          acc[mt][nt] = __builtin_amdgcn_mfma_f32_16x16x32_bf16(a[mt], b[nt], acc[mt][nt], 0, 0, 0);
    }
  }

  #pragma unroll
  for (int mt = 0; mt < 4; ++mt)
    #pragma unroll
    for (int nt = 0; nt < 4; ++nt)
      #pragma unroll
      for (int r = 0; r < 4; ++r) {
        int m = bm + wm + mt * 16 + lg * 4 + r;
        int n = bn + wn + nt * 16 + lr;
        out[(size_t)m * DIMSZ + n] = acc[mt][nt][r];
      }
}

extern "C" void kernel_launch(void* const* d_in, const int* in_sizes, int n_in,
                              void* d_out, int out_size, void* d_ws, size_t ws_size,
                              hipStream_t stream) {
  (void)in_sizes; (void)n_in; (void)out_size; (void)ws_size;
  const float* x  = (const float*)d_in[0];
  const float* Wq = (const float*)d_in[1];
  const float* Wk = (const float*)d_in[2];
  const float* Wv = (const float*)d_in[3];
  const float* Wo = (const float*)d_in[4];
  float* out = (float*)d_out;

  char* ws = (char*)d_ws;
  ushort* qb    = (ushort*)(ws);                       // 8 MB
  ushort* kb    = (ushort*)(ws + ((size_t)8  << 20));  // 8 MB
  ushort* vtb   = (ushort*)(ws + ((size_t)16 << 20));  // 8 MB
  ushort* xb    = (ushort*)(ws + ((size_t)24 << 20));  // 8 MB (xb, reused as ab)
  ushort* ab    = xb;                                  // lifetime disjoint
  ushort* wqkvb = (ushort*)(ws + ((size_t)32 << 20));  // 6 MB
  ushort* wob   = (ushort*)(ws + ((size_t)38 << 20));  // 2 MB
  float2* rtab  = (float2*)(ws + ((size_t)40 << 20));  // 512 KB

  hipLaunchKernelGGL(cvt_k, dim3(4096), dim3(256), 0, stream,
                     x, Wq, Wk, Wv, Wo, xb, wqkvb, wob);
  hipLaunchKernelGGL(rope_table_k, dim3(S_LEN * 32 / 256), dim3(256), 0, stream, rtab);
  hipLaunchKernelGGL(gemm_qkv_k, dim3(8, 32, 3), dim3(256), 0, stream,
                     xb, wqkvb, qb, kb, vtb, rtab);
  hipLaunchKernelGGL(flash_k, dim3(16, 32), dim3(256), 0, stream, qb, kb, vtb, ab);
  hipLaunchKernelGGL(gemm_out_k, dim3(8, 32), dim3(256), 0, stream, ab, wob, out);
}

// Round 4
// 144.618 us; speedup vs baseline: 1.8120x; 1.1560x over previous
//
#include <hip/hip_runtime.h>
#include <hip/hip_bf16.h>

#define S_LEN 2048
#define DIMSZ 1024
#define NH    16
#define HD    64

typedef __attribute__((ext_vector_type(8))) short short8v;
typedef __attribute__((ext_vector_type(4))) short short4v;
typedef __attribute__((ext_vector_type(4))) float f32x4;

typedef const __attribute__((address_space(1))) unsigned GU;
typedef __attribute__((address_space(3))) unsigned LU;

__device__ __forceinline__ void gl16(const ushort* g, ushort* l) {
  __builtin_amdgcn_global_load_lds((GU*)g, (LU*)l, 16, 0, 0);
}

__device__ __forceinline__ ushort f2bf(float f) {
  union { float f; unsigned u; } v; v.f = f;
  unsigned u = v.u;
  return (ushort)((u + 0x7FFFu + ((u >> 16) & 1u)) >> 16);
}

// ---------------- fp32 -> bf16 pre-convert (x, Wq|Wk|Wv, Wo) --------------
__global__ __launch_bounds__(256) void cvt_k(
    const float* __restrict__ x, const float* __restrict__ wq,
    const float* __restrict__ wk, const float* __restrict__ wv,
    const float* __restrict__ wo,
    ushort* __restrict__ xb, ushort* __restrict__ wqkvb, ushort* __restrict__ wob)
{
  size_t gid = (size_t)blockIdx.x * 256 + threadIdx.x;
  size_t e0 = gid * 8;
  const float* src; ushort* dst;
  if (e0 < (4u << 20)) { src = x + e0; dst = xb + e0; }
  else if (e0 < (7u << 20)) {
    size_t o = e0 - (4u << 20);
    const float* w = (o < (1u << 20)) ? wq : ((o < (2u << 20)) ? wk : wv);
    src = w + (o & ((1u << 20) - 1)); dst = wqkvb + o;
  } else {
    size_t o = e0 - (7u << 20);
    src = wo + o; dst = wob + o;
  }
  float4 a = *(const float4*)src;
  float4 b = *(const float4*)(src + 4);
  short8v h;
  h[0] = (short)f2bf(a.x); h[1] = (short)f2bf(a.y);
  h[2] = (short)f2bf(a.z); h[3] = (short)f2bf(a.w);
  h[4] = (short)f2bf(b.x); h[5] = (short)f2bf(b.y);
  h[6] = (short)f2bf(b.z); h[7] = (short)f2bf(b.w);
  *(short8v*)dst = h;
}

// -------- RoPE cos/sin table, [f][s] layout: tab[f*2048+s] = {cos,sin} ----
__global__ __launch_bounds__(256) void rope_table_k(float2* __restrict__ tab) {
  int i = blockIdx.x * 256 + threadIdx.x;      // < 32*2048
  int f = i >> 11, s = i & (S_LEN - 1);
  float inv = powf(10000.f, -(float)f * (1.f / 32.f));
  float ang = (float)s * inv;
  tab[i] = make_float2(cosf(ang), sinf(ang));
}

// ---------------- QKV projection + RoPE, bf16 MFMA GEMM -------------------
// acc = mfma(Wfrag, xfrag): lane lr -> x-row (s), regs -> 4 consecutive W-rows (d)
#define QSTAGE(c, kt_) do {                                                     \
    int k0_ = (kt_) * 64;                                                       \
    _Pragma("unroll")                                                           \
    for (int j_ = 0; j_ < 4; ++j_) {                                            \
      int R_ = w * 32 + j_ * 8;                                                 \
      gl16(xb + (size_t)(bm + R_ + r8) * DIMSZ + k0_ + cswz, &lA[c][R_ * 64]);  \
      gl16(W  + (size_t)(bn + R_ + r8) * DIMSZ + k0_ + cswz, &lB[c][R_ * 64]);  \
    }                                                                           \
  } while (0)

__global__ __launch_bounds__(256) void gemm_qkv_k(
    const ushort* __restrict__ xb, const ushort* __restrict__ wqkvb,
    ushort* __restrict__ qb, ushort* __restrict__ kb, ushort* __restrict__ vtb,
    const float2* __restrict__ rtab)
{
  __shared__ ushort lA[2][128 * 64];
  __shared__ ushort lB[2][128 * 64];
  const int t = threadIdx.x;
  // XCD-chunked swizzle over 768 blocks (8 chunks of 96)
  int id = blockIdx.x;
  int nid = (id & 7) * 96 + (id >> 3);
  const int which = nid >> 8;
  const int bm = ((nid >> 3) & 31) * 128, bn = (nid & 7) * 128;
  const ushort* W = wqkvb + ((size_t)which << 20);
  const int w = t >> 6, l = t & 63, lr = l & 15, lg = l >> 4;
  const int wm = (w >> 1) * 64, wn = (w & 1) * 64;
  const int r8 = l >> 3;
  const int cswz = ((l & 7) ^ r8) * 8;

  f32x4 acc[4][4] = {};

  QSTAGE(0, 0);
  __syncthreads();
  for (int kt = 0; kt < DIMSZ / 64; ++kt) {
    const int cur = kt & 1;
    if (kt + 1 < DIMSZ / 64) QSTAGE(cur ^ 1, kt + 1);
    #pragma unroll
    for (int kk = 0; kk < 2; ++kk) {
      short8v a[4], b[4];
      #pragma unroll
      for (int mt = 0; mt < 4; ++mt) {
        int row = wm + mt * 16 + lr;
        a[mt] = *(const short8v*)((const char*)lA[cur] + row * 128 + ((kk * 64 + lg * 16) ^ ((row & 7) << 4)));
      }
      #pragma unroll
      for (int nt = 0; nt < 4; ++nt) {
        int row = wn + nt * 16 + lr;
        b[nt] = *(const short8v*)((const char*)lB[cur] + row * 128 + ((kk * 64 + lg * 16) ^ ((row & 7) << 4)));
      }
      #pragma unroll
      for (int mt = 0; mt < 4; ++mt)
        #pragma unroll
        for (int nt = 0; nt < 4; ++nt)
          acc[mt][nt] = __builtin_amdgcn_mfma_f32_16x16x32_bf16(b[nt], a[mt], acc[mt][nt], 0, 0, 0);
    }
    __syncthreads();
  }

  const int bb = bm >> 11, s_base = bm & (S_LEN - 1);

  if (which == 2) {
    // V: transpose via LDS bounce -> coalesced [bh][d][s] stores
    ushort* tb = &lA[0][0];   // 32 KB (lA[0]+lA[1] contiguous)
    #pragma unroll
    for (int mt = 0; mt < 4; ++mt)
      #pragma unroll
      for (int nt = 0; nt < 4; ++nt)
        #pragma unroll
        for (int r = 0; r < 4; ++r) {
          int row = wn + nt * 16 + lg * 4 + r;     // d-side 0..127
          int col = wm + mt * 16 + lr;             // s-side 0..127
          int byte = row * 256 + ((col * 2) ^ (((row >> 2) & 3) << 5));
          *(ushort*)((char*)tb + byte) = f2bf(acc[mt][nt][r]);
        }
    __syncthreads();
    int row = t >> 1, half = t & 1;
    int h = (bn + row) >> 6, d = (bn + row) & 63;
    ushort* vdst = vtb + ((size_t)(bb * NH + h) * HD + d) * S_LEN + s_base + half * 64;
    #pragma unroll
    for (int j = 0; j < 8; ++j) {
      int byte = row * 256 + ((half * 128 + j * 16) ^ (((row >> 2) & 3) << 5));
      *(short8v*)(vdst + j * 8) = *(const short8v*)((const char*)tb + byte);
    }
  } else {
    // Q/K: in-lane RoPE (pairs are adjacent regs), packed dwordx2 stores
    ushort* dst = (which == 0) ? qb : kb;
    #pragma unroll
    for (int mt = 0; mt < 4; ++mt) {
      int s = s_base + wm + mt * 16 + lr;
      #pragma unroll
      for (int nt = 0; nt < 4; ++nt) {
        int nw = bn + wn + nt * 16 + lg * 4;
        int h = nw >> 6, d0 = nw & 63;
        uint pk[2];
        #pragma unroll
        for (int rp = 0; rp < 2; ++rp) {
          float2 cs = rtab[(d0 >> 1) * S_LEN + rp * S_LEN + s];
          float t1 = acc[mt][nt][2 * rp], t2 = acc[mt][nt][2 * rp + 1];
          float o0 = t1 * cs.x - t2 * cs.y;
          float o1 = t1 * cs.y + t2 * cs.x;
          pk[rp] = (uint)f2bf(o0) | ((uint)f2bf(o1) << 16);
        }
        uint2 pv; pv.x = pk[0]; pv.y = pk[1];
        *(uint2*)(dst + ((size_t)(bb * NH + h) * S_LEN + s) * HD + d0) = pv;
      }
    }
  }
}

// ---------------- Flash attention (causal), paired q-tiles ----------------
__device__ __forceinline__ void attn_tile(
    const ushort* lK, const ushort* lV, ushort* lPw,
    const short8v* qf, f32x4* o, float& m2, float& lsum,
    int lr, int lg, bool diag, int wrow)
{
  f32x4 sacc[4] = {};
  #pragma unroll
  for (int kk = 0; kk < 2; ++kk)
    #pragma unroll
    for (int jt = 0; jt < 4; ++jt) {
      int row = jt * 16 + lr;
      short8v kf = *(const short8v*)((const char*)lK + row * 128 + ((kk * 64 + lg * 16) ^ ((row & 7) << 4)));
      sacc[jt] = __builtin_amdgcn_mfma_f32_16x16x32_bf16(kf, qf[kk], sacc[jt], 0, 0, 0);
    }
  const float SC = 0.125f * 1.4426950408889634f;  // scale * log2(e)
  float v2[4][4];
  float rmax = -3e38f;
  #pragma unroll
  for (int jt = 0; jt < 4; ++jt)
    #pragma unroll
    for (int r = 0; r < 4; ++r) {
      float sv = sacc[jt][r] * SC;
      if (diag && (jt * 16 + lg * 4 + r > wrow + lr)) sv = -3e38f;
      v2[jt][r] = sv;
      rmax = fmaxf(rmax, sv);
    }
  rmax = fmaxf(rmax, __shfl_xor(rmax, 16));
  rmax = fmaxf(rmax, __shfl_xor(rmax, 32));
  float mn = fmaxf(m2, rmax);
  float so = exp2f(m2 - mn);
  m2 = mn;
  float pe[4][4];
  float ps = 0.f;
  #pragma unroll
  for (int jt = 0; jt < 4; ++jt)
    #pragma unroll
    for (int r = 0; r < 4; ++r) {
      pe[jt][r] = exp2f(v2[jt][r] - mn);
      ps += pe[jt][r];
    }
  ps += __shfl_xor(ps, 16);
  ps += __shfl_xor(ps, 32);
  lsum = lsum * so + ps;
  #pragma unroll
  for (int jt = 0; jt < 4; ++jt) {
    short4v h;
    #pragma unroll
    for (int r = 0; r < 4; ++r) h[r] = (short)f2bf(pe[jt][r]);
    *(short4v*)((char*)lPw + lr * 128 + ((jt * 32 + lg * 8) ^ ((lr & 7) << 4))) = h;
  }
  #pragma unroll
  for (int r = 0; r < 4; ++r) {
    float sor = __shfl(so, lg * 4 + r);
    #pragma unroll
    for (int dt = 0; dt < 4; ++dt) o[dt][r] *= sor;
  }
  #pragma unroll
  for (int kk = 0; kk < 2; ++kk) {
    short8v pa = *(const short8v*)((const char*)lPw + lr * 128 + ((kk * 64 + lg * 16) ^ ((lr & 7) << 4)));
    #pragma unroll
    for (int dt = 0; dt < 4; ++dt) {
      int row = dt * 16 + lr;
      short8v vb = *(const short8v*)((const char*)lV + row * 128 + ((kk * 64 + lg * 16) ^ ((row & 7) << 4)));
      o[dt] = __builtin_amdgcn_mfma_f32_16x16x32_bf16(pa, vb, o[dt], 0, 0, 0);
    }
  }
}

__device__ __forceinline__ void store_tile(
    ushort* __restrict__ ab, int bh, int qt, int w, int lr, int lg,
    const f32x4* o, float lsum)
{
  int b = bh >> 4, h = bh & 15;
  #pragma unroll
  for (int r = 0; r < 4; ++r) {
    float li = __shfl(lsum, lg * 4 + r);
    float inv = 1.f / li;
    int qg = qt * 64 + w * 16 + lg * 4 + r;
    #pragma unroll
    for (int dt = 0; dt < 4; ++dt)
      ab[((size_t)b * S_LEN + qg) * DIMSZ + h * HD + dt * 16 + lr] = f2bf(o[dt][r] * inv);
  }
}

#define STAGE(c, ktile) do {                                                  \
    int kk0_ = (ktile) * 64;                                                  \
    _Pragma("unroll")                                                         \
    for (int j_ = 0; j_ < 2; ++j_) {                                          \
      int R_ = w * 16 + j_ * 8;                                               \
      gl16(kbh + (size_t)(kk0_ + R_ + r8) * HD + cswz, &lKb[c][R_ * 64]);     \
      gl16(vbh + (size_t)(R_ + r8) * S_LEN + kk0_ + cswz, &lVb[c][R_ * 64]);  \
    }                                                                         \
  } while (0)

__global__ __launch_bounds__(256) void flash_k(
    const ushort* __restrict__ qb, const ushort* __restrict__ kb,
    const ushort* __restrict__ vtb, ushort* __restrict__ ab)
{
  __shared__ ushort lKb[2][64 * 64];
  __shared__ ushort lVb[2][64 * 64];
  __shared__ ushort lP[4][16 * 64];

  int id = blockIdx.y * 16 + blockIdx.x;
  int nid = (id & 7) * 64 + (id >> 3);
  const int pr = nid & 15, bh = nid >> 4;
  const int qtA = pr, qtB = 31 - pr;
  const int NT = qtB + 1;

  const int t = threadIdx.x, w = t >> 6, l = t & 63, lr = l & 15, lg = l >> 4;
  const int r8 = l >> 3;
  const int cswz = ((l & 7) ^ r8) * 8;
  const ushort* kbh = kb + (size_t)bh * S_LEN * HD;
  const ushort* vbh = vtb + (size_t)bh * HD * S_LEN;

  short8v qfA[2], qfB[2];
  #pragma unroll
  for (int kk = 0; kk < 2; ++kk) {
    qfA[kk] = *(const short8v*)(qb + ((size_t)bh * S_LEN + qtA * 64 + w * 16 + lr) * HD + kk * 32 + lg * 8);
    qfB[kk] = *(const short8v*)(qb + ((size_t)bh * S_LEN + qtB * 64 + w * 16 + lr) * HD + kk * 32 + lg * 8);
  }

  float mA = -3e38f, lsA = 0.f, mB = -3e38f, lsB = 0.f;
  f32x4 oA[4] = {}, oB[4] = {};

  STAGE(0, 0);
  asm volatile("s_waitcnt vmcnt(0)" ::: "memory");

  for (int kt = 0; kt < NT; ++kt) {
    const int cur = kt & 1;
    if (kt + 1 < NT) {
      STAGE(cur ^ 1, kt + 1);
      asm volatile("s_waitcnt vmcnt(4)" ::: "memory");
    } else {
      asm volatile("s_waitcnt vmcnt(0)" ::: "memory");
    }
    __builtin_amdgcn_s_barrier();
    asm volatile("" ::: "memory");
    const ushort* lK = lKb[cur];
    const ushort* lV = lVb[cur];
    attn_tile(lK, lV, lP[w], qfB, oB, mB, lsB, lr, lg, kt == qtB, w * 16);
    if (kt <= qtA)
      attn_tile(lK, lV, lP[w], qfA, oA, mA, lsA, lr, lg, kt == qtA, w * 16);
    __builtin_amdgcn_s_barrier();
    asm volatile("" ::: "memory");
  }

  store_tile(ab, bh, qtB, w, lr, lg, oB, lsB);
  store_tile(ab, bh, qtA, w, lr, lg, oA, lsA);
}

// ---------------- Output projection: out = ab @ Wo^T (fp32 out) -----------
#define OSTAGE(c, kt_) do {                                                     \
    int k0_ = (kt_) * 64;                                                       \
    _Pragma("unroll")                                                           \
    for (int j_ = 0; j_ < 4; ++j_) {                                            \
      int R_ = w * 32 + j_ * 8;                                                 \
      gl16(ab  + (size_t)(bm + R_ + r8) * DIMSZ + k0_ + cswz, &lA[c][R_ * 64]); \
      gl16(wob + (size_t)(bn + R_ + r8) * DIMSZ + k0_ + cswz, &lB[c][R_ * 64]); \
    }                                                                           \
  } while (0)

__global__ __launch_bounds__(256) void gemm_out_k(
    const ushort* __restrict__ ab, const ushort* __restrict__ wob, float* __restrict__ out)
{
  __shared__ ushort lA[2][128 * 64];
  __shared__ ushort lB[2][128 * 64];
  const int t = threadIdx.x;
  int id = blockIdx.x;
  int nid = (id & 7) * 32 + (id >> 3);
  const int bm = (nid >> 3) * 128, bn = (nid & 7) * 128;
  const int w = t >> 6, l = t & 63, lr = l & 15, lg = l >> 4;
  const int wm = (w >> 1) * 64, wn = (w & 1) * 64;
  const int r8 = l >> 3;
  const int cswz = ((l & 7) ^ r8) * 8;

  f32x4 acc[4][4] = {};

  OSTAGE(0, 0);
  __syncthreads();
  for (int kt = 0; kt < DIMSZ / 64; ++kt) {
    const int cur = kt & 1;
    if (kt + 1 < DIMSZ / 64) OSTAGE(cur ^ 1, kt + 1);
    #pragma unroll
    for (int kk = 0; kk < 2; ++kk) {
      short8v a[4], b[4];
      #pragma unroll
      for (int mt = 0; mt < 4; ++mt) {
        int row = wm + mt * 16 + lr;
        a[mt] = *(const short8v*)((const char*)lA[cur] + row * 128 + ((kk * 64 + lg * 16) ^ ((row & 7) << 4)));
      }
      #pragma unroll
      for (int nt = 0; nt < 4; ++nt) {
        int row = wn + nt * 16 + lr;
        b[nt] = *(const short8v*)((const char*)lB[cur] + row * 128 + ((kk * 64 + lg * 16) ^ ((row & 7) << 4)));
      }
      #pragma unroll
      for (int mt = 0; mt < 4; ++mt)
        #pragma unroll
        for (int nt = 0; nt < 4; ++nt)
          acc[mt][nt] = __builtin_amdgcn_mfma_f32_16x16x32_bf16(b[nt], a[mt], acc[mt][nt], 0, 0, 0);
    }
    __syncthreads();
  }

  #pragma unroll
  for (int mt = 0; mt < 4; ++mt) {
    int m = bm + wm + mt * 16 + lr;
    #pragma unroll
    for (int nt = 0; nt < 4; ++nt) {
      int nb = bn + wn + nt * 16 + lg * 4;
      *(f32x4*)(out + (size_t)m * DIMSZ + nb) = acc[mt][nt];
    }
  }
}

extern "C" void kernel_launch(void* const* d_in, const int* in_sizes, int n_in,
                              void* d_out, int out_size, void* d_ws, size_t ws_size,
                              hipStream_t stream) {
  (void)in_sizes; (void)n_in; (void)out_size; (void)ws_size;
  const float* x  = (const float*)d_in[0];
  const float* Wq = (const float*)d_in[1];
  const float* Wk = (const float*)d_in[2];
  const float* Wv = (const float*)d_in[3];
  const float* Wo = (const float*)d_in[4];
  float* out = (float*)d_out;

  char* ws = (char*)d_ws;
  ushort* qb    = (ushort*)(ws);                       // 8 MB
  ushort* kb    = (ushort*)(ws + ((size_t)8  << 20));  // 8 MB
  ushort* vtb   = (ushort*)(ws + ((size_t)16 << 20));  // 8 MB
  ushort* xb    = (ushort*)(ws + ((size_t)24 << 20));  // 8 MB (xb, reused as ab)
  ushort* ab    = xb;                                  // lifetime disjoint
  ushort* wqkvb = (ushort*)(ws + ((size_t)32 << 20));  // 6 MB
  ushort* wob   = (ushort*)(ws + ((size_t)38 << 20));  // 2 MB
  float2* rtab  = (float2*)(ws + ((size_t)40 << 20));  // 512 KB

  hipLaunchKernelGGL(cvt_k, dim3(4096), dim3(256), 0, stream,
                     x, Wq, Wk, Wv, Wo, xb, wqkvb, wob);
  hipLaunchKernelGGL(rope_table_k, dim3(S_LEN * 32 / 256), dim3(256), 0, stream, rtab);
  hipLaunchKernelGGL(gemm_qkv_k, dim3(768), dim3(256), 0, stream,
                     xb, wqkvb, qb, kb, vtb, rtab);
  hipLaunchKernelGGL(flash_k, dim3(16, 32), dim3(256), 0, stream, qb, kb, vtb, ab);
  hipLaunchKernelGGL(gemm_out_k, dim3(256), dim3(256), 0, stream, ab, wob, out);
}

// Round 5
// 138.188 us; speedup vs baseline: 1.8963x; 1.0465x over previous
//
#include <hip/hip_runtime.h>
#include <hip/hip_bf16.h>

#define S_LEN 2048
#define DIMSZ 1024
#define NH    16
#define HD    64

typedef __attribute__((ext_vector_type(8))) short short8v;
typedef __attribute__((ext_vector_type(4))) short short4v;
typedef __attribute__((ext_vector_type(4))) float f32x4;

typedef const __attribute__((address_space(1))) unsigned GU;
typedef __attribute__((address_space(3))) unsigned LU;

__device__ __forceinline__ void gl16(const ushort* g, ushort* l) {
  __builtin_amdgcn_global_load_lds((GU*)g, (LU*)l, 16, 0, 0);
}

__device__ __forceinline__ ushort f2bf(float f) {
  union { float f; unsigned u; } v; v.f = f;
  unsigned u = v.u;
  return (ushort)((u + 0x7FFFu + ((u >> 16) & 1u)) >> 16);
}

__device__ __forceinline__ uint cvtpk(float lo, float hi) {
  uint d;
  asm("v_cvt_pk_bf16_f32 %0, %1, %2" : "=v"(d) : "v"(lo), "v"(hi));
  return d;
}

// ---------------- fp32 -> bf16 pre-convert (x, Wq|Wk|Wv, Wo) --------------
__global__ __launch_bounds__(256) void cvt_k(
    const float* __restrict__ x, const float* __restrict__ wq,
    const float* __restrict__ wk, const float* __restrict__ wv,
    const float* __restrict__ wo,
    ushort* __restrict__ xb, ushort* __restrict__ wqkvb, ushort* __restrict__ wob)
{
  size_t gid = (size_t)blockIdx.x * 256 + threadIdx.x;
  size_t e0 = gid * 8;
  const float* src; ushort* dst;
  if (e0 < (4u << 20)) { src = x + e0; dst = xb + e0; }
  else if (e0 < (7u << 20)) {
    size_t o = e0 - (4u << 20);
    const float* w = (o < (1u << 20)) ? wq : ((o < (2u << 20)) ? wk : wv);
    src = w + (o & ((1u << 20) - 1)); dst = wqkvb + o;
  } else {
    size_t o = e0 - (7u << 20);
    src = wo + o; dst = wob + o;
  }
  float4 a = *(const float4*)src;
  float4 b = *(const float4*)(src + 4);
  short8v h;
  h[0] = (short)f2bf(a.x); h[1] = (short)f2bf(a.y);
  h[2] = (short)f2bf(a.z); h[3] = (short)f2bf(a.w);
  h[4] = (short)f2bf(b.x); h[5] = (short)f2bf(b.y);
  h[6] = (short)f2bf(b.z); h[7] = (short)f2bf(b.w);
  *(short8v*)dst = h;
}

// -------- RoPE cos/sin table, [f][s] layout: tab[f*2048+s] = {cos,sin} ----
__global__ __launch_bounds__(256) void rope_table_k(float2* __restrict__ tab) {
  int i = blockIdx.x * 256 + threadIdx.x;      // < 32*2048
  int f = i >> 11, s = i & (S_LEN - 1);
  float inv = powf(10000.f, -(float)f * (1.f / 32.f));
  float ang = (float)s * inv;
  tab[i] = make_float2(cosf(ang), sinf(ang));
}

// ---------------- QKV projection + RoPE, bf16 MFMA GEMM -------------------
#define QSTAGE(c, kt_) do {                                                     \
    int k0_ = (kt_) * 64;                                                       \
    _Pragma("unroll")                                                           \
    for (int j_ = 0; j_ < 4; ++j_) {                                            \
      int R_ = w * 32 + j_ * 8;                                                 \
      gl16(xb + (size_t)(bm + R_ + r8) * DIMSZ + k0_ + cswz, &lA[c][R_ * 64]);  \
      gl16(W  + (size_t)(bn + R_ + r8) * DIMSZ + k0_ + cswz, &lB[c][R_ * 64]);  \
    }                                                                           \
  } while (0)

__global__ __launch_bounds__(256) void gemm_qkv_k(
    const ushort* __restrict__ xb, const ushort* __restrict__ wqkvb,
    ushort* __restrict__ qb, ushort* __restrict__ kb, ushort* __restrict__ vtb,
    const float2* __restrict__ rtab)
{
  __shared__ ushort lA[2][128 * 64];
  __shared__ ushort lB[2][128 * 64];
  const int t = threadIdx.x;
  int id = blockIdx.x;
  int nid = (id & 7) * 96 + (id >> 3);
  const int which = nid >> 8;
  const int bm = ((nid >> 3) & 31) * 128, bn = (nid & 7) * 128;
  const ushort* W = wqkvb + ((size_t)which << 20);
  const int w = t >> 6, l = t & 63, lr = l & 15, lg = l >> 4;
  const int wm = (w >> 1) * 64, wn = (w & 1) * 64;
  const int r8 = l >> 3;
  const int cswz = ((l & 7) ^ r8) * 8;

  f32x4 acc[4][4] = {};

  QSTAGE(0, 0);
  __syncthreads();
  for (int kt = 0; kt < DIMSZ / 64; ++kt) {
    const int cur = kt & 1;
    if (kt + 1 < DIMSZ / 64) QSTAGE(cur ^ 1, kt + 1);
    #pragma unroll
    for (int kk = 0; kk < 2; ++kk) {
      short8v a[4], b[4];
      #pragma unroll
      for (int mt = 0; mt < 4; ++mt) {
        int row = wm + mt * 16 + lr;
        a[mt] = *(const short8v*)((const char*)lA[cur] + row * 128 + ((kk * 64 + lg * 16) ^ ((row & 7) << 4)));
      }
      #pragma unroll
      for (int nt = 0; nt < 4; ++nt) {
        int row = wn + nt * 16 + lr;
        b[nt] = *(const short8v*)((const char*)lB[cur] + row * 128 + ((kk * 64 + lg * 16) ^ ((row & 7) << 4)));
      }
      #pragma unroll
      for (int mt = 0; mt < 4; ++mt)
        #pragma unroll
        for (int nt = 0; nt < 4; ++nt)
          acc[mt][nt] = __builtin_amdgcn_mfma_f32_16x16x32_bf16(b[nt], a[mt], acc[mt][nt], 0, 0, 0);
    }
    __syncthreads();
  }

  const int bb = bm >> 11, s_base = bm & (S_LEN - 1);

  if (which == 2) {
    // V: transpose via LDS bounce -> coalesced [bh][d][s] stores
    ushort* tb = &lA[0][0];
    #pragma unroll
    for (int mt = 0; mt < 4; ++mt)
      #pragma unroll
      for (int nt = 0; nt < 4; ++nt)
        #pragma unroll
        for (int r = 0; r < 4; ++r) {
          int row = wn + nt * 16 + lg * 4 + r;     // d-side 0..127
          int col = wm + mt * 16 + lr;             // s-side 0..127
          int byte = row * 256 + ((col * 2) ^ (((row >> 2) & 3) << 5));
          *(ushort*)((char*)tb + byte) = f2bf(acc[mt][nt][r]);
        }
    __syncthreads();
    int row = t >> 1, half = t & 1;
    int h = (bn + row) >> 6, d = (bn + row) & 63;
    ushort* vdst = vtb + ((size_t)(bb * NH + h) * HD + d) * S_LEN + s_base + half * 64;
    #pragma unroll
    for (int j = 0; j < 8; ++j) {
      int byte = row * 256 + ((half * 128 + j * 16) ^ (((row >> 2) & 3) << 5));
      *(short8v*)(vdst + j * 8) = *(const short8v*)((const char*)tb + byte);
    }
  } else {
    // Q/K: in-lane RoPE; Q additionally pre-scaled by 0.125*log2(e)
    ushort* dst = (which == 0) ? qb : kb;
    const float QS = (which == 0) ? (0.125f * 1.4426950408889634f) : 1.0f;
    #pragma unroll
    for (int mt = 0; mt < 4; ++mt) {
      int s = s_base + wm + mt * 16 + lr;
      #pragma unroll
      for (int nt = 0; nt < 4; ++nt) {
        int nw = bn + wn + nt * 16 + lg * 4;
        int h = nw >> 6, d0 = nw & 63;
        uint pk[2];
        #pragma unroll
        for (int rp = 0; rp < 2; ++rp) {
          float2 cs = rtab[(d0 >> 1) * S_LEN + rp * S_LEN + s];
          float t1 = acc[mt][nt][2 * rp], t2 = acc[mt][nt][2 * rp + 1];
          float o0 = (t1 * cs.x - t2 * cs.y) * QS;
          float o1 = (t1 * cs.y + t2 * cs.x) * QS;
          pk[rp] = (uint)f2bf(o0) | ((uint)f2bf(o1) << 16);
        }
        uint2 pv; pv.x = pk[0]; pv.y = pk[1];
        *(uint2*)(dst + ((size_t)(bb * NH + h) * S_LEN + s) * HD + d0) = pv;
      }
    }
  }
}

// ---------------- Flash attention (causal), paired q-tiles ----------------
// scores arrive already in log2 units (Q pre-scaled); defer-max THR=8
template<bool DIAG>
__device__ __forceinline__ void attn_tile(
    const ushort* lK, const ushort* lV, ushort* lPw,
    const short8v* qf, f32x4* o, float& m2, float& lsum,
    int lr, int lg, int wrow)
{
  f32x4 sacc[4] = {};
  __builtin_amdgcn_s_setprio(1);
  #pragma unroll
  for (int kk = 0; kk < 2; ++kk)
    #pragma unroll
    for (int jt = 0; jt < 4; ++jt) {
      int row = jt * 16 + lr;
      short8v kf = *(const short8v*)((const char*)lK + row * 128 + ((kk * 64 + lg * 16) ^ ((row & 7) << 4)));
      sacc[jt] = __builtin_amdgcn_mfma_f32_16x16x32_bf16(kf, qf[kk], sacc[jt], 0, 0, 0);
    }
  __builtin_amdgcn_s_setprio(0);

  float v2[4][4];
  #pragma unroll
  for (int jt = 0; jt < 4; ++jt)
    #pragma unroll
    for (int r = 0; r < 4; ++r) {
      float sv = sacc[jt][r];
      if (DIAG && (jt * 16 + lg * 4 + r > wrow + lr)) sv = -3e38f;
      v2[jt][r] = sv;
    }
  float mj[4];
  #pragma unroll
  for (int jt = 0; jt < 4; ++jt)
    mj[jt] = fmaxf(fmaxf(v2[jt][0], v2[jt][1]), fmaxf(v2[jt][2], v2[jt][3]));
  float rmax = fmaxf(fmaxf(mj[0], mj[1]), fmaxf(mj[2], mj[3]));
  rmax = fmaxf(rmax, __shfl_xor(rmax, 16));
  rmax = fmaxf(rmax, __shfl_xor(rmax, 32));

  const bool need = __any(rmax > m2 + 8.f);
  float mn = m2;
  float so = 1.f;
  if (need) {
    mn = fmaxf(m2, rmax);
    so = exp2f(m2 - mn);
    m2 = mn;
  }
  float pe[4][4];
  float ps = 0.f;
  #pragma unroll
  for (int jt = 0; jt < 4; ++jt)
    #pragma unroll
    for (int r = 0; r < 4; ++r) {
      pe[jt][r] = exp2f(v2[jt][r] - mn);
      ps += pe[jt][r];
    }
  ps += __shfl_xor(ps, 16);
  ps += __shfl_xor(ps, 32);
  if (need) {
    lsum = lsum * so + ps;
    #pragma unroll
    for (int r = 0; r < 4; ++r) {
      float sor = __shfl(so, lg * 4 + r);
      #pragma unroll
      for (int dt = 0; dt < 4; ++dt) o[dt][r] *= sor;
    }
  } else {
    lsum += ps;
  }
  #pragma unroll
  for (int jt = 0; jt < 4; ++jt) {
    uint2 pv;
    pv.x = cvtpk(pe[jt][0], pe[jt][1]);
    pv.y = cvtpk(pe[jt][2], pe[jt][3]);
    *(uint2*)((char*)lPw + lr * 128 + ((jt * 32 + lg * 8) ^ ((lr & 7) << 4))) = pv;
  }
  __builtin_amdgcn_s_setprio(1);
  #pragma unroll
  for (int kk = 0; kk < 2; ++kk) {
    short8v pa = *(const short8v*)((const char*)lPw + lr * 128 + ((kk * 64 + lg * 16) ^ ((lr & 7) << 4)));
    #pragma unroll
    for (int dt = 0; dt < 4; ++dt) {
      int row = dt * 16 + lr;
      short8v vb = *(const short8v*)((const char*)lV + row * 128 + ((kk * 64 + lg * 16) ^ ((row & 7) << 4)));
      o[dt] = __builtin_amdgcn_mfma_f32_16x16x32_bf16(pa, vb, o[dt], 0, 0, 0);
    }
  }
  __builtin_amdgcn_s_setprio(0);
}

__device__ __forceinline__ void store_tile(
    ushort* __restrict__ ab, int bh, int qt, int w, int lr, int lg,
    const f32x4* o, float lsum)
{
  int b = bh >> 4, h = bh & 15;
  #pragma unroll
  for (int r = 0; r < 4; ++r) {
    float li = __shfl(lsum, lg * 4 + r);
    float inv = 1.f / li;
    int qg = qt * 64 + w * 16 + lg * 4 + r;
    #pragma unroll
    for (int dt = 0; dt < 4; ++dt)
      ab[((size_t)b * S_LEN + qg) * DIMSZ + h * HD + dt * 16 + lr] = f2bf(o[dt][r] * inv);
  }
}

#define STAGE(c, ktile) do {                                                  \
    int kk0_ = (ktile) * 64;                                                  \
    _Pragma("unroll")                                                         \
    for (int j_ = 0; j_ < 2; ++j_) {                                          \
      int R_ = w * 16 + j_ * 8;                                               \
      gl16(kbh + (size_t)(kk0_ + R_ + r8) * HD + cswz, &lKb[c][R_ * 64]);     \
      gl16(vbh + (size_t)(R_ + r8) * S_LEN + kk0_ + cswz, &lVb[c][R_ * 64]);  \
    }                                                                         \
  } while (0)

__global__ __launch_bounds__(256) void flash_k(
    const ushort* __restrict__ qb, const ushort* __restrict__ kb,
    const ushort* __restrict__ vtb, ushort* __restrict__ ab)
{
  __shared__ ushort lKb[2][64 * 64];
  __shared__ ushort lVb[2][64 * 64];
  __shared__ ushort lP[4][16 * 64];

  int id = blockIdx.y * 16 + blockIdx.x;
  int nid = (id & 7) * 64 + (id >> 3);
  const int pr = nid & 15, bh = nid >> 4;
  const int qtA = pr, qtB = 31 - pr;
  const int NT = qtB + 1;

  const int t = threadIdx.x, w = t >> 6, l = t & 63, lr = l & 15, lg = l >> 4;
  const int r8 = l >> 3;
  const int cswz = ((l & 7) ^ r8) * 8;
  const ushort* kbh = kb + (size_t)bh * S_LEN * HD;
  const ushort* vbh = vtb + (size_t)bh * HD * S_LEN;

  short8v qfA[2], qfB[2];
  #pragma unroll
  for (int kk = 0; kk < 2; ++kk) {
    qfA[kk] = *(const short8v*)(qb + ((size_t)bh * S_LEN + qtA * 64 + w * 16 + lr) * HD + kk * 32 + lg * 8);
    qfB[kk] = *(const short8v*)(qb + ((size_t)bh * S_LEN + qtB * 64 + w * 16 + lr) * HD + kk * 32 + lg * 8);
  }

  float mA = -3e38f, lsA = 0.f, mB = -3e38f, lsB = 0.f;
  f32x4 oA[4] = {}, oB[4] = {};

  STAGE(0, 0);
  asm volatile("s_waitcnt vmcnt(0)" ::: "memory");

  for (int kt = 0; kt < NT; ++kt) {
    const int cur = kt & 1;
    if (kt + 1 < NT) {
      STAGE(cur ^ 1, kt + 1);
      asm volatile("s_waitcnt vmcnt(4)" ::: "memory");
    } else {
      asm volatile("s_waitcnt vmcnt(0)" ::: "memory");
    }
    __builtin_amdgcn_s_barrier();
    asm volatile("" ::: "memory");
    const ushort* lK = lKb[cur];
    const ushort* lV = lVb[cur];
    if (kt == qtB) attn_tile<true >(lK, lV, lP[w], qfB, oB, mB, lsB, lr, lg, w * 16);
    else           attn_tile<false>(lK, lV, lP[w], qfB, oB, mB, lsB, lr, lg, w * 16);
    if (kt <= qtA) {
      if (kt == qtA) attn_tile<true >(lK, lV, lP[w], qfA, oA, mA, lsA, lr, lg, w * 16);
      else           attn_tile<false>(lK, lV, lP[w], qfA, oA, mA, lsA, lr, lg, w * 16);
    }
    __builtin_amdgcn_s_barrier();
    asm volatile("" ::: "memory");
  }

  store_tile(ab, bh, qtB, w, lr, lg, oB, lsB);
  store_tile(ab, bh, qtA, w, lr, lg, oA, lsA);
}

// ---------------- Output projection: out = ab @ Wo^T (fp32 out) -----------
#define OSTAGE(c, kt_) do {                                                     \
    int k0_ = (kt_) * 64;                                                       \
    _Pragma("unroll")                                                           \
    for (int j_ = 0; j_ < 4; ++j_) {                                            \
      int R_ = w * 32 + j_ * 8;                                                 \
      gl16(ab  + (size_t)(bm + R_ + r8) * DIMSZ + k0_ + cswz, &lA[c][R_ * 64]); \
      gl16(wob + (size_t)(bn + R_ + r8) * DIMSZ + k0_ + cswz, &lB[c][R_ * 64]); \
    }                                                                           \
  } while (0)

__global__ __launch_bounds__(256) void gemm_out_k(
    const ushort* __restrict__ ab, const ushort* __restrict__ wob, float* __restrict__ out)
{
  __shared__ ushort lA[2][128 * 64];
  __shared__ ushort lB[2][128 * 64];
  const int t = threadIdx.x;
  int id = blockIdx.x;
  int nid = (id & 7) * 32 + (id >> 3);
  const int bm = (nid >> 3) * 128, bn = (nid & 7) * 128;
  const int w = t >> 6, l = t & 63, lr = l & 15, lg = l >> 4;
  const int wm = (w >> 1) * 64, wn = (w & 1) * 64;
  const int r8 = l >> 3;
  const int cswz = ((l & 7) ^ r8) * 8;

  f32x4 acc[4][4] = {};

  OSTAGE(0, 0);
  __syncthreads();
  for (int kt = 0; kt < DIMSZ / 64; ++kt) {
    const int cur = kt & 1;
    if (kt + 1 < DIMSZ / 64) OSTAGE(cur ^ 1, kt + 1);
    #pragma unroll
    for (int kk = 0; kk < 2; ++kk) {
      short8v a[4], b[4];
      #pragma unroll
      for (int mt = 0; mt < 4; ++mt) {
        int row = wm + mt * 16 + lr;
        a[mt] = *(const short8v*)((const char*)lA[cur] + row * 128 + ((kk * 64 + lg * 16) ^ ((row & 7) << 4)));
      }
      #pragma unroll
      for (int nt = 0; nt < 4; ++nt) {
        int row = wn + nt * 16 + lr;
        b[nt] = *(const short8v*)((const char*)lB[cur] + row * 128 + ((kk * 64 + lg * 16) ^ ((row & 7) << 4)));
      }
      #pragma unroll
      for (int mt = 0; mt < 4; ++mt)
        #pragma unroll
        for (int nt = 0; nt < 4; ++nt)
          acc[mt][nt] = __builtin_amdgcn_mfma_f32_16x16x32_bf16(b[nt], a[mt], acc[mt][nt], 0, 0, 0);
    }
    __syncthreads();
  }

  #pragma unroll
  for (int mt = 0; mt < 4; ++mt) {
    int m = bm + wm + mt * 16 + lr;
    #pragma unroll
    for (int nt = 0; nt < 4; ++nt) {
      int nb = bn + wn + nt * 16 + lg * 4;
      *(f32x4*)(out + (size_t)m * DIMSZ + nb) = acc[mt][nt];
    }
  }
}

extern "C" void kernel_launch(void* const* d_in, const int* in_sizes, int n_in,
                              void* d_out, int out_size, void* d_ws, size_t ws_size,
                              hipStream_t stream) {
  (void)in_sizes; (void)n_in; (void)out_size; (void)ws_size;
  const float* x  = (const float*)d_in[0];
  const float* Wq = (const float*)d_in[1];
  const float* Wk = (const float*)d_in[2];
  const float* Wv = (const float*)d_in[3];
  const float* Wo = (const float*)d_in[4];
  float* out = (float*)d_out;

  char* ws = (char*)d_ws;
  ushort* qb    = (ushort*)(ws);                       // 8 MB
  ushort* kb    = (ushort*)(ws + ((size_t)8  << 20));  // 8 MB
  ushort* vtb   = (ushort*)(ws + ((size_t)16 << 20));  // 8 MB
  ushort* xb    = (ushort*)(ws + ((size_t)24 << 20));  // 8 MB (xb, reused as ab)
  ushort* ab    = xb;                                  // lifetime disjoint
  ushort* wqkvb = (ushort*)(ws + ((size_t)32 << 20));  // 6 MB
  ushort* wob   = (ushort*)(ws + ((size_t)38 << 20));  // 2 MB
  float2* rtab  = (float2*)(ws + ((size_t)40 << 20));  // 512 KB

  hipLaunchKernelGGL(cvt_k, dim3(4096), dim3(256), 0, stream,
                     x, Wq, Wk, Wv, Wo, xb, wqkvb, wob);
  hipLaunchKernelGGL(rope_table_k, dim3(S_LEN * 32 / 256), dim3(256), 0, stream, rtab);
  hipLaunchKernelGGL(gemm_qkv_k, dim3(768), dim3(256), 0, stream,
                     xb, wqkvb, qb, kb, vtb, rtab);
  hipLaunchKernelGGL(flash_k, dim3(16, 32), dim3(256), 0, stream, qb, kb, vtb, ab);
  hipLaunchKernelGGL(gemm_out_k, dim3(256), dim3(256), 0, stream, ab, wob, out);
}

// Round 6
// 132.016 us; speedup vs baseline: 1.9850x; 1.0468x over previous
//
#include <hip/hip_runtime.h>
#include <hip/hip_bf16.h>

#define S_LEN 2048
#define DIMSZ 1024
#define NH    16
#define HD    64

typedef __attribute__((ext_vector_type(8))) short short8v;
typedef __attribute__((ext_vector_type(4))) short short4v;
typedef __attribute__((ext_vector_type(4))) float f32x4;

typedef const __attribute__((address_space(1))) unsigned GU;
typedef __attribute__((address_space(3))) unsigned LU;

__device__ __forceinline__ void gl16(const ushort* g, ushort* l) {
  __builtin_amdgcn_global_load_lds((GU*)g, (LU*)l, 16, 0, 0);
}

__device__ __forceinline__ ushort f2bf(float f) {
  union { float f; unsigned u; } v; v.f = f;
  unsigned u = v.u;
  return (ushort)((u + 0x7FFFu + ((u >> 16) & 1u)) >> 16);
}

__device__ __forceinline__ uint cvtpk(float lo, float hi) {
  uint d;
  asm("v_cvt_pk_bf16_f32 %0, %1, %2" : "=v"(d) : "v"(lo), "v"(hi));
  return d;
}

// ---------------- fp32 -> bf16 pre-convert (x, Wq|Wk|Wv, Wo) --------------
__global__ __launch_bounds__(256) void cvt_k(
    const float* __restrict__ x, const float* __restrict__ wq,
    const float* __restrict__ wk, const float* __restrict__ wv,
    const float* __restrict__ wo,
    ushort* __restrict__ xb, ushort* __restrict__ wqkvb, ushort* __restrict__ wob)
{
  size_t gid = (size_t)blockIdx.x * 256 + threadIdx.x;
  size_t e0 = gid * 8;
  const float* src; ushort* dst;
  if (e0 < (4u << 20)) { src = x + e0; dst = xb + e0; }
  else if (e0 < (7u << 20)) {
    size_t o = e0 - (4u << 20);
    const float* w = (o < (1u << 20)) ? wq : ((o < (2u << 20)) ? wk : wv);
    src = w + (o & ((1u << 20) - 1)); dst = wqkvb + o;
  } else {
    size_t o = e0 - (7u << 20);
    src = wo + o; dst = wob + o;
  }
  float4 a = *(const float4*)src;
  float4 b = *(const float4*)(src + 4);
  short8v h;
  h[0] = (short)f2bf(a.x); h[1] = (short)f2bf(a.y);
  h[2] = (short)f2bf(a.z); h[3] = (short)f2bf(a.w);
  h[4] = (short)f2bf(b.x); h[5] = (short)f2bf(b.y);
  h[6] = (short)f2bf(b.z); h[7] = (short)f2bf(b.w);
  *(short8v*)dst = h;
}

// -------- RoPE cos/sin table, [f][s] layout: tab[f*2048+s] = {cos,sin} ----
__global__ __launch_bounds__(256) void rope_table_k(float2* __restrict__ tab) {
  int i = blockIdx.x * 256 + threadIdx.x;      // < 32*2048
  int f = i >> 11, s = i & (S_LEN - 1);
  float inv = powf(10000.f, -(float)f * (1.f / 32.f));
  float ang = (float)s * inv;
  tab[i] = make_float2(cosf(ang), sinf(ang));
}

// ---------------- QKV projection + RoPE, bf16 MFMA GEMM -------------------
#define QSTAGE(c, kt_) do {                                                     \
    int k0_ = (kt_) * 64;                                                       \
    _Pragma("unroll")                                                           \
    for (int j_ = 0; j_ < 4; ++j_) {                                            \
      int R_ = w * 32 + j_ * 8;                                                 \
      gl16(xb + (size_t)(bm + R_ + r8) * DIMSZ + k0_ + cswz, &lA[c][R_ * 64]);  \
      gl16(W  + (size_t)(bn + R_ + r8) * DIMSZ + k0_ + cswz, &lB[c][R_ * 64]);  \
    }                                                                           \
  } while (0)

__global__ __launch_bounds__(256) void gemm_qkv_k(
    const ushort* __restrict__ xb, const ushort* __restrict__ wqkvb,
    ushort* __restrict__ qb, ushort* __restrict__ kb, ushort* __restrict__ vtb,
    const float2* __restrict__ rtab)
{
  __shared__ ushort lA[2][128 * 64];
  __shared__ ushort lB[2][128 * 64];
  const int t = threadIdx.x;
  int id = blockIdx.x;
  int nid = (id & 7) * 96 + (id >> 3);
  const int which = nid >> 8;
  const int bm = ((nid >> 3) & 31) * 128, bn = (nid & 7) * 128;
  const ushort* W = wqkvb + ((size_t)which << 20);
  const int w = t >> 6, l = t & 63, lr = l & 15, lg = l >> 4;
  const int wm = (w >> 1) * 64, wn = (w & 1) * 64;
  const int r8 = l >> 3;
  const int cswz = ((l & 7) ^ r8) * 8;

  f32x4 acc[4][4] = {};

  QSTAGE(0, 0);
  __syncthreads();
  for (int kt = 0; kt < DIMSZ / 64; ++kt) {
    const int cur = kt & 1;
    if (kt + 1 < DIMSZ / 64) QSTAGE(cur ^ 1, kt + 1);
    #pragma unroll
    for (int kk = 0; kk < 2; ++kk) {
      short8v a[4], b[4];
      #pragma unroll
      for (int mt = 0; mt < 4; ++mt) {
        int row = wm + mt * 16 + lr;
        a[mt] = *(const short8v*)((const char*)lA[cur] + row * 128 + ((kk * 64 + lg * 16) ^ ((row & 7) << 4)));
      }
      #pragma unroll
      for (int nt = 0; nt < 4; ++nt) {
        int row = wn + nt * 16 + lr;
        b[nt] = *(const short8v*)((const char*)lB[cur] + row * 128 + ((kk * 64 + lg * 16) ^ ((row & 7) << 4)));
      }
      #pragma unroll
      for (int mt = 0; mt < 4; ++mt)
        #pragma unroll
        for (int nt = 0; nt < 4; ++nt)
          acc[mt][nt] = __builtin_amdgcn_mfma_f32_16x16x32_bf16(b[nt], a[mt], acc[mt][nt], 0, 0, 0);
    }
    __syncthreads();
  }

  const int bb = bm >> 11, s_base = bm & (S_LEN - 1);

  if (which == 2) {
    // V: transpose via LDS bounce -> coalesced [bh][d][s] stores
    ushort* tb = &lA[0][0];
    #pragma unroll
    for (int mt = 0; mt < 4; ++mt)
      #pragma unroll
      for (int nt = 0; nt < 4; ++nt)
        #pragma unroll
        for (int r = 0; r < 4; ++r) {
          int row = wn + nt * 16 + lg * 4 + r;     // d-side 0..127
          int col = wm + mt * 16 + lr;             // s-side 0..127
          int byte = row * 256 + ((col * 2) ^ (((row >> 2) & 3) << 5));
          *(ushort*)((char*)tb + byte) = f2bf(acc[mt][nt][r]);
        }
    __syncthreads();
    int row = t >> 1, half = t & 1;
    int h = (bn + row) >> 6, d = (bn + row) & 63;
    ushort* vdst = vtb + ((size_t)(bb * NH + h) * HD + d) * S_LEN + s_base + half * 64;
    #pragma unroll
    for (int j = 0; j < 8; ++j) {
      int byte = row * 256 + ((half * 128 + j * 16) ^ (((row >> 2) & 3) << 5));
      *(short8v*)(vdst + j * 8) = *(const short8v*)((const char*)tb + byte);
    }
  } else {
    // Q/K: in-lane RoPE; Q additionally pre-scaled by 0.125*log2(e)
    ushort* dst = (which == 0) ? qb : kb;
    const float QS = (which == 0) ? (0.125f * 1.4426950408889634f) : 1.0f;
    #pragma unroll
    for (int mt = 0; mt < 4; ++mt) {
      int s = s_base + wm + mt * 16 + lr;
      #pragma unroll
      for (int nt = 0; nt < 4; ++nt) {
        int nw = bn + wn + nt * 16 + lg * 4;
        int h = nw >> 6, d0 = nw & 63;
        uint pk[2];
        #pragma unroll
        for (int rp = 0; rp < 2; ++rp) {
          float2 cs = rtab[(d0 >> 1) * S_LEN + rp * S_LEN + s];
          float t1 = acc[mt][nt][2 * rp], t2 = acc[mt][nt][2 * rp + 1];
          float o0 = (t1 * cs.x - t2 * cs.y) * QS;
          float o1 = (t1 * cs.y + t2 * cs.x) * QS;
          pk[rp] = (uint)f2bf(o0) | ((uint)f2bf(o1) << 16);
        }
        uint2 pv; pv.x = pk[0]; pv.y = pk[1];
        *(uint2*)(dst + ((size_t)(bb * NH + h) * S_LEN + s) * HD + d0) = pv;
      }
    }
  }
}

// ---------------- Flash attention (causal), 8-wave / 2-group split --------
// scores arrive already in log2 units (Q pre-scaled); defer-max THR=8
template<bool DIAG>
__device__ __forceinline__ void attn_tile(
    const ushort* lK, const ushort* lV, ushort* lPw,
    const short8v* qf, f32x4* o, float& m2, float& lsum,
    int lr, int lg, int wrow)
{
  f32x4 sacc[4] = {};
  __builtin_amdgcn_s_setprio(1);
  #pragma unroll
  for (int kk = 0; kk < 2; ++kk)
    #pragma unroll
    for (int jt = 0; jt < 4; ++jt) {
      int row = jt * 16 + lr;
      short8v kf = *(const short8v*)((const char*)lK + row * 128 + ((kk * 64 + lg * 16) ^ ((row & 7) << 4)));
      sacc[jt] = __builtin_amdgcn_mfma_f32_16x16x32_bf16(kf, qf[kk], sacc[jt], 0, 0, 0);
    }
  __builtin_amdgcn_s_setprio(0);

  float v2[4][4];
  #pragma unroll
  for (int jt = 0; jt < 4; ++jt)
    #pragma unroll
    for (int r = 0; r < 4; ++r) {
      float sv = sacc[jt][r];
      if (DIAG && (jt * 16 + lg * 4 + r > wrow + lr)) sv = -3e38f;
      v2[jt][r] = sv;
    }
  float mj[4];
  #pragma unroll
  for (int jt = 0; jt < 4; ++jt)
    mj[jt] = fmaxf(fmaxf(v2[jt][0], v2[jt][1]), fmaxf(v2[jt][2], v2[jt][3]));
  float rmax = fmaxf(fmaxf(mj[0], mj[1]), fmaxf(mj[2], mj[3]));
  rmax = fmaxf(rmax, __shfl_xor(rmax, 16));
  rmax = fmaxf(rmax, __shfl_xor(rmax, 32));

  const bool need = __any(rmax > m2 + 8.f);
  float mn = m2;
  float so = 1.f;
  if (need) {
    mn = fmaxf(m2, rmax);
    so = exp2f(m2 - mn);
    m2 = mn;
  }
  float pe[4][4];
  float ps = 0.f;
  #pragma unroll
  for (int jt = 0; jt < 4; ++jt)
    #pragma unroll
    for (int r = 0; r < 4; ++r) {
      pe[jt][r] = exp2f(v2[jt][r] - mn);
      ps += pe[jt][r];
    }
  ps += __shfl_xor(ps, 16);
  ps += __shfl_xor(ps, 32);
  if (need) {
    lsum = lsum * so + ps;
    #pragma unroll
    for (int r = 0; r < 4; ++r) {
      float sor = __shfl(so, lg * 4 + r);
      #pragma unroll
      for (int dt = 0; dt < 4; ++dt) o[dt][r] *= sor;
    }
  } else {
    lsum += ps;
  }
  #pragma unroll
  for (int jt = 0; jt < 4; ++jt) {
    uint2 pv;
    pv.x = cvtpk(pe[jt][0], pe[jt][1]);
    pv.y = cvtpk(pe[jt][2], pe[jt][3]);
    *(uint2*)((char*)lPw + lr * 128 + ((jt * 32 + lg * 8) ^ ((lr & 7) << 4))) = pv;
  }
  __builtin_amdgcn_s_setprio(1);
  #pragma unroll
  for (int kk = 0; kk < 2; ++kk) {
    short8v pa = *(const short8v*)((const char*)lPw + lr * 128 + ((kk * 64 + lg * 16) ^ ((lr & 7) << 4)));
    #pragma unroll
    for (int dt = 0; dt < 4; ++dt) {
      int row = dt * 16 + lr;
      short8v vb = *(const short8v*)((const char*)lV + row * 128 + ((kk * 64 + lg * 16) ^ ((row & 7) << 4)));
      o[dt] = __builtin_amdgcn_mfma_f32_16x16x32_bf16(pa, vb, o[dt], 0, 0, 0);
    }
  }
  __builtin_amdgcn_s_setprio(0);
}

// item i of combined stream [B0..BqtB, A0..AqtA] -> KV tile index
#define ITEM_KT(i_) (((i_) <= qtB) ? (i_) : ((i_) - qtB - 1))

#define FSTAGE(c, rnd) do {                                                   \
    int i0_ = (rnd) * 2, i1_ = i0_ + 1;                                       \
    int ka_ = ITEM_KT(i0_) * 64;                                              \
    int kb_ = ((i1_ <= 32) ? ITEM_KT(i1_) : 0) * 64;                          \
    gl16(kbh + (size_t)(ka_ + trow) * HD + cswz,    &lKb[c][0][w * 512]);     \
    gl16(kbh + (size_t)(kb_ + trow) * HD + cswz,    &lKb[c][1][w * 512]);     \
    gl16(vbh + (size_t)trow * S_LEN + ka_ + cswz,   &lVb[c][0][w * 512]);     \
    gl16(vbh + (size_t)trow * S_LEN + kb_ + cswz,   &lVb[c][1][w * 512]);     \
  } while (0)

__global__ __launch_bounds__(512, 4) void flash_k(
    const ushort* __restrict__ qb, const ushort* __restrict__ kb,
    const ushort* __restrict__ vtb, ushort* __restrict__ ab)
{
  __shared__ ushort lKb[2][2][64 * 64];   // [slot][item-in-round]
  __shared__ ushort lVb[2][2][64 * 64];
  __shared__ ushort lP[8][16 * 64];

  int id = blockIdx.y * 16 + blockIdx.x;
  int nid = (id & 7) * 64 + (id >> 3);
  const int pr = nid & 15, bh = nid >> 4;
  const int qtA = pr, qtB = 31 - pr;      // NT_A + NT_B = 33 items

  const int t = threadIdx.x, w = t >> 6, l = t & 63, lr = l & 15, lg = l >> 4;
  const int g = w >> 2, ws = w & 3;       // group, row-slice
  const int r8 = l >> 3;
  const int cswz = ((l & 7) ^ r8) * 8;
  const int trow = t >> 3;                // 0..63
  const ushort* kbh = kb + (size_t)bh * S_LEN * HD;
  const ushort* vbh = vtb + (size_t)bh * HD * S_LEN;

  short8v qfA[2], qfB[2];
  #pragma unroll
  for (int kk = 0; kk < 2; ++kk) {
    qfA[kk] = *(const short8v*)(qb + ((size_t)bh * S_LEN + qtA * 64 + ws * 16 + lr) * HD + kk * 32 + lg * 8);
    qfB[kk] = *(const short8v*)(qb + ((size_t)bh * S_LEN + qtB * 64 + ws * 16 + lr) * HD + kk * 32 + lg * 8);
  }

  float mA = -3e38f, lsA = 0.f, mB = -3e38f, lsB = 0.f;
  f32x4 oA[4] = {}, oB[4] = {};

  FSTAGE(0, 0);
  asm volatile("s_waitcnt vmcnt(0)" ::: "memory");

  const int NR = 17;
  for (int rnd = 0; rnd < NR; ++rnd) {
    const int cur = rnd & 1;
    if (rnd + 1 < NR) {
      FSTAGE(cur ^ 1, rnd + 1);
      asm volatile("s_waitcnt vmcnt(4)" ::: "memory");
    } else {
      asm volatile("s_waitcnt vmcnt(0)" ::: "memory");
    }
    __builtin_amdgcn_s_barrier();
    asm volatile("" ::: "memory");
    const int it = 2 * rnd + g;
    if (it <= 32) {
      const ushort* lK = lKb[cur][g];
      const ushort* lV = lVb[cur][g];
      if (it <= qtB) {
        if (it == qtB) attn_tile<true >(lK, lV, lP[w], qfB, oB, mB, lsB, lr, lg, ws * 16);
        else           attn_tile<false>(lK, lV, lP[w], qfB, oB, mB, lsB, lr, lg, ws * 16);
      } else {
        const int ka = it - qtB - 1;
        if (ka == qtA) attn_tile<true >(lK, lV, lP[w], qfA, oA, mA, lsA, lr, lg, ws * 16);
        else           attn_tile<false>(lK, lV, lP[w], qfA, oA, mA, lsA, lr, lg, ws * 16);
      }
    }
    __builtin_amdgcn_s_barrier();
    asm volatile("" ::: "memory");
  }

  // ---- cross-group merge: partials through retired K/V LDS ----
  float* obB = (float*)&lKb[0][0][0];     // 32 KB: 8 blocks of 16x64 f32
  float* obA = (float*)&lVb[0][0][0];
  float* ml  = (float*)&lP[0][0];         // [member][blk][row][2]
  const int blk = g * 4 + ws;
  #pragma unroll
  for (int dt = 0; dt < 4; ++dt)
    #pragma unroll
    for (int r = 0; r < 4; ++r) {
      obB[blk * 1024 + (lg * 4 + r) * 64 + dt * 16 + lr] = oB[dt][r];
      obA[blk * 1024 + (lg * 4 + r) * 64 + dt * 16 + lr] = oA[dt][r];
    }
  if (lg == 0) {
    ml[(blk * 16 + lr) * 2 + 0] = mB;  ml[(blk * 16 + lr) * 2 + 1] = lsB;
    ml[512 + (blk * 16 + lr) * 2 + 0] = mA;  ml[512 + (blk * 16 + lr) * 2 + 1] = lsA;
  }
  __syncthreads();

  // group 0 finalizes member B, group 1 member A
  const float* mlm = ml + (g ? 512 : 0);
  const float* o0  = (g ? obA : obB) + ws * 1024;
  const float* o1  = (g ? obA : obB) + (4 + ws) * 1024;
  const int qt = g ? qtA : qtB;
  const int b = bh >> 4, h = bh & 15;
  #pragma unroll
  for (int r = 0; r < 4; ++r) {
    int row = lg * 4 + r;
    float m0 = mlm[(ws * 16 + row) * 2 + 0], l0 = mlm[(ws * 16 + row) * 2 + 1];
    float m1 = mlm[((4 + ws) * 16 + row) * 2 + 0], l1 = mlm[((4 + ws) * 16 + row) * 2 + 1];
    float msr = fmaxf(m0, m1);
    float a0 = exp2f(m0 - msr), a1 = exp2f(m1 - msr);
    float inv = 1.f / (l0 * a0 + l1 * a1);
    int qg = qt * 64 + ws * 16 + row;
    #pragma unroll
    for (int dt = 0; dt < 4; ++dt) {
      float v = o0[row * 64 + dt * 16 + lr] * a0 + o1[row * 64 + dt * 16 + lr] * a1;
      ab[((size_t)b * S_LEN + qg) * DIMSZ + h * HD + dt * 16 + lr] = f2bf(v * inv);
    }
  }
}

// ---------------- Output projection: out = ab @ Wo^T (fp32 out) -----------
#define OSTAGE(c, kt_) do {                                                     \
    int k0_ = (kt_) * 64;                                                       \
    _Pragma("unroll")                                                           \
    for (int j_ = 0; j_ < 4; ++j_) {                                            \
      int R_ = w * 32 + j_ * 8;                                                 \
      gl16(ab  + (size_t)(bm + R_ + r8) * DIMSZ + k0_ + cswz, &lA[c][R_ * 64]); \
      gl16(wob + (size_t)(bn + R_ + r8) * DIMSZ + k0_ + cswz, &lB[c][R_ * 64]); \
    }                                                                           \
  } while (0)

__global__ __launch_bounds__(256) void gemm_out_k(
    const ushort* __restrict__ ab, const ushort* __restrict__ wob, float* __restrict__ out)
{
  __shared__ ushort lA[2][128 * 64];
  __shared__ ushort lB[2][128 * 64];
  const int t = threadIdx.x;
  int id = blockIdx.x;
  int nid = (id & 7) * 32 + (id >> 3);
  const int bm = (nid >> 3) * 128, bn = (nid & 7) * 128;
  const int w = t >> 6, l = t & 63, lr = l & 15, lg = l >> 4;
  const int wm = (w >> 1) * 64, wn = (w & 1) * 64;
  const int r8 = l >> 3;
  const int cswz = ((l & 7) ^ r8) * 8;

  f32x4 acc[4][4] = {};

  OSTAGE(0, 0);
  __syncthreads();
  for (int kt = 0; kt < DIMSZ / 64; ++kt) {
    const int cur = kt & 1;
    if (kt + 1 < DIMSZ / 64) OSTAGE(cur ^ 1, kt + 1);
    #pragma unroll
    for (int kk = 0; kk < 2; ++kk) {
      short8v a[4], b[4];
      #pragma unroll
      for (int mt = 0; mt < 4; ++mt) {
        int row = wm + mt * 16 + lr;
        a[mt] = *(const short8v*)((const char*)lA[cur] + row * 128 + ((kk * 64 + lg * 16) ^ ((row & 7) << 4)));
      }
      #pragma unroll
      for (int nt = 0; nt < 4; ++nt) {
        int row = wn + nt * 16 + lr;
        b[nt] = *(const short8v*)((const char*)lB[cur] + row * 128 + ((kk * 64 + lg * 16) ^ ((row & 7) << 4)));
      }
      #pragma unroll
      for (int mt = 0; mt < 4; ++mt)
        #pragma unroll
        for (int nt = 0; nt < 4; ++nt)
          acc[mt][nt] = __builtin_amdgcn_mfma_f32_16x16x32_bf16(b[nt], a[mt], acc[mt][nt], 0, 0, 0);
    }
    __syncthreads();
  }

  #pragma unroll
  for (int mt = 0; mt < 4; ++mt) {
    int m = bm + wm + mt * 16 + lr;
    #pragma unroll
    for (int nt = 0; nt < 4; ++nt) {
      int nb = bn + wn + nt * 16 + lg * 4;
      *(f32x4*)(out + (size_t)m * DIMSZ + nb) = acc[mt][nt];
    }
  }
}

extern "C" void kernel_launch(void* const* d_in, const int* in_sizes, int n_in,
                              void* d_out, int out_size, void* d_ws, size_t ws_size,
                              hipStream_t stream) {
  (void)in_sizes; (void)n_in; (void)out_size; (void)ws_size;
  const float* x  = (const float*)d_in[0];
  const float* Wq = (const float*)d_in[1];
  const float* Wk = (const float*)d_in[2];
  const float* Wv = (const float*)d_in[3];
  const float* Wo = (const float*)d_in[4];
  float* out = (float*)d_out;

  char* ws = (char*)d_ws;
  ushort* qb    = (ushort*)(ws);                       // 8 MB
  ushort* kb    = (ushort*)(ws + ((size_t)8  << 20));  // 8 MB
  ushort* vtb   = (ushort*)(ws + ((size_t)16 << 20));  // 8 MB
  ushort* xb    = (ushort*)(ws + ((size_t)24 << 20));  // 8 MB (xb, reused as ab)
  ushort* ab    = xb;                                  // lifetime disjoint
  ushort* wqkvb = (ushort*)(ws + ((size_t)32 << 20));  // 6 MB
  ushort* wob   = (ushort*)(ws + ((size_t)38 << 20));  // 2 MB
  float2* rtab  = (float2*)(ws + ((size_t)40 << 20));  // 512 KB

  hipLaunchKernelGGL(cvt_k, dim3(4096), dim3(256), 0, stream,
                     x, Wq, Wk, Wv, Wo, xb, wqkvb, wob);
  hipLaunchKernelGGL(rope_table_k, dim3(S_LEN * 32 / 256), dim3(256), 0, stream, rtab);
  hipLaunchKernelGGL(gemm_qkv_k, dim3(768), dim3(256), 0, stream,
                     xb, wqkvb, qb, kb, vtb, rtab);
  hipLaunchKernelGGL(flash_k, dim3(16, 32), dim3(512), 0, stream, qb, kb, vtb, ab);
  hipLaunchKernelGGL(gemm_out_k, dim3(256), dim3(256), 0, stream, ab, wob, out);
}